// Round 15
// baseline (156.781 us; speedup 1.0000x reference)
//
#include <hip/hip_runtime.h>

// ---------- problem constants ----------
#define BQ   8
#define NQ   8192      // unknown points per batch
#define MK   2048      // known points per batch
#define C1v  128
#define C2v  256
#define CIN  384
#define HH   256
#define MTOT (BQ*NQ)   // 65536

#define NCHUNK 8       // candidate chunks per nn block (= waves per block)
#define CHSZ   (MK/NCHUNK)   // 256 candidates per chunk

typedef __attribute__((ext_vector_type(8))) __bf16 bf16x8;
typedef __attribute__((ext_vector_type(4))) float f32x4;
typedef __attribute__((ext_vector_type(8))) unsigned short us8;
typedef __attribute__((ext_vector_type(4))) unsigned short us4;
typedef __attribute__((ext_vector_type(2))) unsigned short us2;

__device__ __forceinline__ unsigned short f2bf(float f) {
  unsigned int u = __builtin_bit_cast(unsigned int, f);
  u += 0x7fffu + ((u >> 16) & 1u);           // round-to-nearest-even
  return (unsigned short)(u >> 16);
}
__device__ __forceinline__ float bf2f(unsigned short h) {
  unsigned int u = ((unsigned int)h) << 16;
  return __builtin_bit_cast(float, u);
}

__device__ __forceinline__ void gload16(const void* g, void* l) {
  __builtin_amdgcn_global_load_lds((const __attribute__((address_space(1))) void*)g,
                                   (__attribute__((address_space(3))) void*)l, 16, 0, 0);
}

// packed f32->bf16 RNE convert (dst.lo = src0, dst.hi = src1)
__device__ __forceinline__ unsigned int cvtpk_bf16(float lo, float hi) {
  unsigned int r;
  asm("v_cvt_pk_bf16_f32 %0, %1, %2" : "=v"(r) : "v"(lo), "v"(hi));
  return r;
}

// score from a staged candidate: s = u.k - 0.5|k|^2  (kprep.w = -0.5|k|^2)
#define SCORE(k4) (fmaf((k4).x, ux, fmaf((k4).y, uy, (k4).z * uz)) + (k4).w)

// (score,index) insert, strict > so earlier index wins ties (top_k semantics)
#define TOP3_INS_IDX(c0, c1, c2, e0, e1, e2, s, jj)                  \
  do {                                                               \
    const bool g0 = (s) > c0, g1 = (s) > c1, g2 = (s) > c2;          \
    c2 = g1 ? c1 : (g2 ? (s) : c2);  e2 = g1 ? e1 : (g2 ? (jj) : e2);\
    c1 = g0 ? c0 : (g1 ? (s) : c1);  e1 = g0 ? e0 : (g1 ? (jj) : e1);\
    c0 = g0 ? (s) : c0;              e0 = g0 ? (jj) : e0;            \
  } while (0)

// ---------- 1. prep: W->bf16, BN accum zero, kprep, kf->bf16 (kfb) ----------
__global__ __launch_bounds__(256)
void prep_kernel(const float* __restrict__ W1, const float* __restrict__ W2,
                 const float* __restrict__ known, const float* __restrict__ kf,
                 unsigned short* __restrict__ w1b, unsigned short* __restrict__ w2b,
                 float* __restrict__ stats, float4* __restrict__ kprep,
                 unsigned short* __restrict__ kfb) {
  int i = blockIdx.x * 256 + threadIdx.x;
  if (i < HH*CIN) w1b[i] = f2bf(W1[i]);
  else if (i < HH*CIN + HH*HH) w2b[i - HH*CIN] = f2bf(W2[i - HH*CIN]);
  int z = i - (HH*CIN + HH*HH);
  if (z >= 0 && z < 1024) stats[z] = 0.f;
  int z2 = i - (HH*CIN + HH*HH + 1024);
  if (z2 >= 0 && z2 < BQ*MK) {
    const float* kp = known + (size_t)z2 * 3;
    float x = kp[0], y = kp[1], zz = kp[2];
    kprep[z2] = make_float4(x, y, zz, -0.5f*(x*x + y*y + zz*zz));
  }
  int z3 = i - (HH*CIN + HH*HH + 1024 + BQ*MK);
  if (z3 >= 0 && z3 < (BQ*MK*C2v)/8) {
    const float4* src = (const float4*)(kf + (size_t)z3 * 8);
    float4 v0 = src[0], v1 = src[1];
    us8 o;
    o[0]=f2bf(v0.x); o[1]=f2bf(v0.y); o[2]=f2bf(v0.z); o[3]=f2bf(v0.w);
    o[4]=f2bf(v1.x); o[5]=f2bf(v1.y); o[6]=f2bf(v1.z); o[7]=f2bf(v1.w);
    *(us8*)(kfb + (size_t)z3 * 8) = o;
  }
}

// ---------- 2. three_nn: single pass, f32 (score,idx) cndmask top-3 ----------
// Exact: scores are the same fp32 expression as ever; single ascending-j chain
// with strict > keeps first-occurrence tie order (top_k semantics); merge in
// ascending chunk order preserves it. No f64 (quarter-rate) ops in the loop.
__global__ __launch_bounds__(512)
void nn_kernel(const float* __restrict__ unknown, const float4* __restrict__ kprep,
               int* __restrict__ widx, float* __restrict__ wwgt) {
  __shared__ float ps[NCHUNK][64][3];       // per-chunk triples (scores)
  __shared__ int   pi[NCHUNK][64][3];       // per-chunk triples (indices)
  const int b = blockIdx.y;
  const int tid = threadIdx.x;
  const int wave = tid >> 6, lane = tid & 63;

  const int q = blockIdx.x * 64 + lane;
  const float* up = unknown + ((size_t)b * NQ + q) * 3;
  const float ux = up[0], uy = up[1], uz = up[2];
  const float nu = ux*ux + uy*uy + uz*uz;
  const int jbase = wave * CHSZ;
  // wave-uniform chunk pointer -> scalar-path candidate fetch
  const float4* cp = kprep + (b << 11) + __builtin_amdgcn_readfirstlane(jbase);

  float s0=-3.4e38f, s1=-3.4e38f, s2=-3.4e38f;
  int   i0=0x7fffffff, i1=0x7fffffff, i2=0x7fffffff;
  #pragma unroll 8
  for (int j = 0; j < CHSZ; ++j) {
    float4 k4 = cp[j];
    float s = SCORE(k4);
    const int jj = jbase + j;
    TOP3_INS_IDX(s0, s1, s2, i0, i1, i2, s, jj);
  }
  ps[wave][lane][0]=s0; ps[wave][lane][1]=s1; ps[wave][lane][2]=s2;
  pi[wave][lane][0]=i0; pi[wave][lane][1]=i1; pi[wave][lane][2]=i2;
  __syncthreads();

  if (tid < 64) {   // wave 0: lane == query; merge chunks in ascending index order
    float f0=-3.4e38f, f1=-3.4e38f, f2=-3.4e38f;
    int   x0=0x7fffffff, x1=0x7fffffff, x2=0x7fffffff;
    #pragma unroll
    for (int c = 0; c < NCHUNK; ++c)
      #pragma unroll
      for (int r = 0; r < 3; ++r) {
        float s = ps[c][tid][r]; int jj = pi[c][tid][r];
        TOP3_INS_IDX(f0, f1, f2, x0, x1, x2, s, jj);
      }
    float d0 = sqrtf(fmaxf(nu - 2.f*f0, 0.f)) + 1e-10f;
    float d1 = sqrtf(fmaxf(nu - 2.f*f1, 0.f)) + 1e-10f;
    float d2 = sqrtf(fmaxf(nu - 2.f*f2, 0.f)) + 1e-10f;
    float r0 = 1.f/d0, r1 = 1.f/d1, r2 = 1.f/d2;
    float rs = 1.f/(r0 + r1 + r2);
    size_t p = (size_t)b * NQ + q;
    widx[p*3+0] = x0;    widx[p*3+1] = x1;    widx[p*3+2] = x2;
    wwgt[p*3+0] = r0*rs; wwgt[p*3+1] = r1*rs; wwgt[p*3+2] = r2*rs;
  }
}

// ---------- 3. GEMM1 (fused interp): A built in-staging from bf16-kf gathers
// (3x16B per chunk) + uf concat; cross-phase prefetch pinned by sched_barrier.
// Block swizzle: batch = wid&7 -> all 128 blocks of a batch land on one XCD.
__global__ __launch_bounds__(256)
void gemm1_fused(const unsigned short* __restrict__ kfb, const float* __restrict__ uf,
                 const int* __restrict__ widx, const float* __restrict__ wwgt,
                 const unsigned short* __restrict__ Bw,
                 const float* __restrict__ bias,
                 unsigned short* __restrict__ Out,
                 float* __restrict__ gsum, float* __restrict__ gsq) {
  constexpr int K = CIN;
  __shared__ unsigned short As[128][64];   // 16 KB
  __shared__ unsigned short Bs[128][64];   // 16 KB
  const int tid  = threadIdx.x;
  const int lane = tid & 63;
  const int wave = tid >> 6;          // 0..3
  const int wid   = blockIdx.x;
  const int batch = wid & 7;          // -> XCD id
  const int inner = wid >> 3;         // 0..127 within batch
  const int bm = batch * 64 + (inner >> 1);
  const int bn = inner & 1;
  const int wm = wave >> 1, wn = wave & 1;

  // prologue: per-chunk gather byte-offsets + weights (chunk i -> fixed row/col)
  unsigned int voK0[4], voK1[4], voK2[4], voU[4];
  float w0r[4], w1r[4], w2r[4];
  #pragma unroll
  for (int i = 0; i < 4; ++i) {
    const int c = wave*64 + i*256 + lane;
    const int row = c >> 3;
    const int colK = (c & 7) * 16;     // byte offset within 512 B bf16 row
    const int colU = (c & 7) * 32;     // byte offset within 512 B fp32 row
    const int p = bm*128 + row;
    const int b = p >> 13;
    w0r[i] = wwgt[p*3+0]; w1r[i] = wwgt[p*3+1]; w2r[i] = wwgt[p*3+2];
    voK0[i] = ((unsigned)((b << 11) + widx[p*3+0]) << 9) + colK;
    voK1[i] = ((unsigned)((b << 11) + widx[p*3+1]) << 9) + colK;
    voK2[i] = ((unsigned)((b << 11) + widx[p*3+2]) << 9) + colK;
    voU[i]  = (unsigned)p * 512u + colU;
  }

  f32x4 acc[4][4];
  const f32x4 zero = {0.f, 0.f, 0.f, 0.f};
  #pragma unroll
  for (int m = 0; m < 4; ++m)
    #pragma unroll
    for (int n = 0; n < 4; ++n) acc[m][n] = zero;

  const char* kfbb = (const char*)kfb;
  const char* ufb  = (const char*)uf;

  // ping-pong prefetch registers (indices constant after full unroll)
  us8    PK0[2][4], PK1[2][4], PK2[2][4];
  float4 PU0[2][4], PU1[2][4];

  #pragma unroll
  for (int i = 0; i < 4; ++i) {        // prologue: gathers for t = 0
    PK0[0][i] = *(const us8*)(kfbb + voK0[i]);
    PK1[0][i] = *(const us8*)(kfbb + voK1[i]);
    PK2[0][i] = *(const us8*)(kfbb + voK2[i]);
  }

  #pragma unroll
  for (int t = 0; t < 6; ++t) {
    const int cur = t & 1, nxt = cur ^ 1;
    const int k0 = t * 64;
    // B-tile: async LDS-direct
    #pragma unroll
    for (int i = 0; i < 4; ++i) {
      const int cbase = wave*64 + i*256;
      const int c = cbase + lane;
      const int brow = c >> 3, bcol = (c & 7) * 8;
      gload16(Bw + ((size_t)(bn*128 + brow))*K + k0 + bcol, (unsigned short*)Bs + cbase*8);
    }
    // prefetch A-tile for t+1 into regs; pin issue before the MFMA phase
    if (t < 3) {
      #pragma unroll
      for (int i = 0; i < 4; ++i) {
        PK0[nxt][i] = *(const us8*)(kfbb + voK0[i] + (t+1)*128);
        PK1[nxt][i] = *(const us8*)(kfbb + voK1[i] + (t+1)*128);
        PK2[nxt][i] = *(const us8*)(kfbb + voK2[i] + (t+1)*128);
      }
    } else if (t < 5) {
      #pragma unroll
      for (int i = 0; i < 4; ++i) {
        PU0[nxt][i] = *(const float4*)(ufb + voU[i] + (t-3)*256);
        PU1[nxt][i] = *(const float4*)(ufb + voU[i] + (t-3)*256 + 16);
      }
    }
    __builtin_amdgcn_sched_barrier(0);
    // convert current tile from regs -> LDS
    #pragma unroll
    for (int i = 0; i < 4; ++i) {
      const int c = wave*64 + i*256 + lane;
      uint4 ov;
      if (t < 4) {
        const float w0 = w0r[i], w1 = w1r[i], w2 = w2r[i];
        float r[8];
        #pragma unroll
        for (int j = 0; j < 8; ++j) {
          float fa = bf2f((unsigned short)PK0[cur][i][j]);
          float fe = bf2f((unsigned short)PK1[cur][i][j]);
          float fg = bf2f((unsigned short)PK2[cur][i][j]);
          r[j] = w0*fa + w1*fe + w2*fg;
        }
        ov.x = cvtpk_bf16(r[0], r[1]);
        ov.y = cvtpk_bf16(r[2], r[3]);
        ov.z = cvtpk_bf16(r[4], r[5]);
        ov.w = cvtpk_bf16(r[6], r[7]);
      } else {
        float4 r0 = PU0[cur][i], r1 = PU1[cur][i];
        ov.x = cvtpk_bf16(r0.x, r0.y);
        ov.y = cvtpk_bf16(r0.z, r0.w);
        ov.z = cvtpk_bf16(r1.x, r1.y);
        ov.w = cvtpk_bf16(r1.z, r1.w);
      }
      *(uint4*)((unsigned short*)As + (size_t)c*8) = ov;
    }
    __syncthreads();
    const int kq = (lane >> 4) * 8;
    #pragma unroll
    for (int kk = 0; kk < 64; kk += 32) {
      bf16x8 af[4], bfr[4];
      #pragma unroll
      for (int m = 0; m < 4; ++m)
        af[m] = *(const bf16x8*)&As[wm*64 + m*16 + (lane & 15)][kk + kq];
      #pragma unroll
      for (int n = 0; n < 4; ++n)
        bfr[n] = *(const bf16x8*)&Bs[wn*64 + n*16 + (lane & 15)][kk + kq];
      #pragma unroll
      for (int m = 0; m < 4; ++m)
        #pragma unroll
        for (int n = 0; n < 4; ++n)
          acc[m][n] = __builtin_amdgcn_mfma_f32_16x16x32_bf16(af[m], bfr[n], acc[m][n], 0, 0, 0);
    }
    __syncthreads();
  }

  // epilogue: bias, store bf16, per-channel sum/sumsq
  float* s_sum = (float*)&As[0][0];   // [2][128]
  float* s_sq  = s_sum + 256;         // [2][128]
  #pragma unroll
  for (int n = 0; n < 4; ++n) {
    const int cb   = wn*64 + n*16 + (lane & 15);
    const int gcol = bn*128 + cb;
    const float bv = bias[gcol];
    float sum = 0.f, sq = 0.f;
    #pragma unroll
    for (int m = 0; m < 4; ++m) {
      const size_t grow = (size_t)bm*128 + wm*64 + m*16 + (lane >> 4)*4;
      #pragma unroll
      for (int qq = 0; qq < 4; ++qq) {
        float y = acc[m][n][qq] + bv;
        sum += y; sq += y*y;
        Out[(grow+qq)*256 + gcol] = f2bf(y);
      }
    }
    sum += __shfl_xor(sum, 16, 64); sum += __shfl_xor(sum, 32, 64);
    sq  += __shfl_xor(sq , 16, 64); sq  += __shfl_xor(sq , 32, 64);
    if (lane < 16) { s_sum[wm*128 + cb] = sum; s_sq[wm*128 + cb] = sq; }
  }
  __syncthreads();
  if (tid < 128) {
    atomicAdd(&gsum[bn*128 + tid], s_sum[tid] + s_sum[128 + tid]);
    atomicAdd(&gsq [bn*128 + tid], s_sq [tid] + s_sq [128 + tid]);
  }
}

// ---------- 4. GEMM2: fused BN1+ReLU on A-load (scale/shift computed in preamble
// from raw sums), y2 bf16 out, + BN2 stats ----------
__global__ __launch_bounds__(256)
void gemm2_kernel(const unsigned short* __restrict__ A,     // y1 raw bf16
                  const unsigned short* __restrict__ Bw,    // W2 bf16
                  const float* __restrict__ bias,           // b2
                  unsigned short* __restrict__ Out,         // y2 bf16
                  float* __restrict__ gsum, float* __restrict__ gsq,     // BN2 accum
                  const float* __restrict__ gsum1, const float* __restrict__ gsq1,
                  const float* __restrict__ g1, const float* __restrict__ be1) {
  constexpr int K = HH;
  __shared__ unsigned short As[128][64];   // 16 KB
  __shared__ unsigned short Bs[128][64];   // 16 KB
  __shared__ float sc_l[HH], sh_l[HH];     // 2 KB
  const int tid  = threadIdx.x;
  const int lane = tid & 63;
  const int wave = tid >> 6;          // 0..3
  const int wid  = blockIdx.x;
  const int slot = wid & 15;
  const int bm = ((wid >> 4) << 3) | (slot & 7);
  const int bn = slot >> 3;
  const int wm = wave >> 1, wn = wave & 1;

  {  // BN1 finalize (redundant per block; replaces stats_fin dispatch)
    float mu  = gsum1[tid] * (1.f/65536.f);
    float var = gsq1[tid]  * (1.f/65536.f) - mu*mu;
    float sc  = g1[tid] * rsqrtf(var + 1e-5f);
    sc_l[tid] = sc;
    sh_l[tid] = be1[tid] - mu*sc;
  }
  __syncthreads();

  f32x4 acc[4][4];
  const f32x4 zero = {0.f, 0.f, 0.f, 0.f};
  #pragma unroll
  for (int m = 0; m < 4; ++m)
    #pragma unroll
    for (int n = 0; n < 4; ++n) acc[m][n] = zero;

  for (int k0 = 0; k0 < K; k0 += 64) {
    #pragma unroll
    for (int i = 0; i < 4; ++i) {
      const int cbase = wave*64 + i*256;          // wave-uniform chunk base
      const int c = cbase + lane;                 // per-lane chunk (16 B)
      const int row = c >> 3, col = (c & 7) * 8;
      gload16(Bw + ((size_t)(bn*128 + row))*K + k0 + col, (unsigned short*)Bs + cbase*8);
      us8 v = *(const us8*)(A + ((size_t)(bm*128 + row))*K + k0 + col);
      us8 o;
      #pragma unroll
      for (int j = 0; j < 8; ++j) {
        float y = fmaxf(fmaf(bf2f(v[j]), sc_l[k0+col+j], sh_l[k0+col+j]), 0.f);
        o[j] = f2bf(y);
      }
      *(us8*)((unsigned short*)As + cbase*8 + lane*8) = o;
    }
    __syncthreads();
    const int kq = (lane >> 4) * 8;
    #pragma unroll
    for (int kk = 0; kk < 64; kk += 32) {
      bf16x8 af[4], bfr[4];
      #pragma unroll
      for (int m = 0; m < 4; ++m)
        af[m] = *(const bf16x8*)&As[wm*64 + m*16 + (lane & 15)][kk + kq];
      #pragma unroll
      for (int n = 0; n < 4; ++n)
        bfr[n] = *(const bf16x8*)&Bs[wn*64 + n*16 + (lane & 15)][kk + kq];
      #pragma unroll
      for (int m = 0; m < 4; ++m)
        #pragma unroll
        for (int n = 0; n < 4; ++n)
          acc[m][n] = __builtin_amdgcn_mfma_f32_16x16x32_bf16(af[m], bfr[n], acc[m][n], 0, 0, 0);
    }
    __syncthreads();
  }

  // epilogue: bias, store bf16 y2, per-channel sum/sumsq
  float* s_sum = (float*)&As[0][0];   // [2][128]
  float* s_sq  = s_sum + 256;         // [2][128]
  #pragma unroll
  for (int n = 0; n < 4; ++n) {
    const int cb   = wn*64 + n*16 + (lane & 15);
    const int gcol = bn*128 + cb;
    const float bv = bias[gcol];
    float sum = 0.f, sq = 0.f;
    #pragma unroll
    for (int m = 0; m < 4; ++m) {
      const size_t grow = (size_t)bm*128 + wm*64 + m*16 + (lane >> 4)*4;
      #pragma unroll
      for (int qq = 0; qq < 4; ++qq) {
        float y = acc[m][n][qq] + bv;
        sum += y; sq += y*y;
        Out[(grow+qq)*256 + gcol] = f2bf(y);
      }
    }
    sum += __shfl_xor(sum, 16, 64); sum += __shfl_xor(sum, 32, 64);
    sq  += __shfl_xor(sq , 16, 64); sq  += __shfl_xor(sq , 32, 64);
    if (lane < 16) { s_sum[wm*128 + cb] = sum; s_sq[wm*128 + cb] = sq; }
  }
  __syncthreads();
  if (tid < 128) {
    atomicAdd(&gsum[bn*128 + tid], s_sum[tid] + s_sum[128 + tid]);
    atomicAdd(&gsq [bn*128 + tid], s_sq [tid] + s_sq [128 + tid]);
  }
}

// ---------- 5. final BN2+ReLU: bf16 y2 -> fp32 d_out (scale/shift in preamble) ----------
__global__ __launch_bounds__(256)
void final_kernel(const unsigned short* __restrict__ Y2, float* __restrict__ Out,
                  const float* __restrict__ gsum, const float* __restrict__ gsq,
                  const float* __restrict__ g2, const float* __restrict__ be2) {
  __shared__ float sc[256], sh[256];
  {  // BN2 finalize (redundant per block; replaces stats_fin dispatch)
    float mu  = gsum[threadIdx.x] * (1.f/65536.f);
    float var = gsq[threadIdx.x]  * (1.f/65536.f) - mu*mu;
    float scv = g2[threadIdx.x] * rsqrtf(var + 1e-5f);
    sc[threadIdx.x] = scv;
    sh[threadIdx.x] = be2[threadIdx.x] - mu*scv;
  }
  __syncthreads();
  size_t i = ((size_t)blockIdx.x * 256 + threadIdx.x) * 8;
  int c0 = (int)(i & 255);
  us8 v = *(const us8*)(Y2 + i);
  float4 o1, o2;
  o1.x = fmaxf(fmaf(bf2f(v[0]), sc[c0+0], sh[c0+0]), 0.f);
  o1.y = fmaxf(fmaf(bf2f(v[1]), sc[c0+1], sh[c0+1]), 0.f);
  o1.z = fmaxf(fmaf(bf2f(v[2]), sc[c0+2], sh[c0+2]), 0.f);
  o1.w = fmaxf(fmaf(bf2f(v[3]), sc[c0+3], sh[c0+3]), 0.f);
  o2.x = fmaxf(fmaf(bf2f(v[4]), sc[c0+4], sh[c0+4]), 0.f);
  o2.y = fmaxf(fmaf(bf2f(v[5]), sc[c0+5], sh[c0+5]), 0.f);
  o2.z = fmaxf(fmaf(bf2f(v[6]), sc[c0+6], sh[c0+6]), 0.f);
  o2.w = fmaxf(fmaf(bf2f(v[7]), sc[c0+7], sh[c0+7]), 0.f);
  *(float4*)(Out + i)     = o1;
  *(float4*)(Out + i + 4) = o2;
}

// ---------- launch ----------
extern "C" void kernel_launch(void* const* d_in, const int* in_sizes, int n_in,
                              void* d_out, int out_size, void* d_ws, size_t ws_size,
                              hipStream_t stream) {
  const float* unknown = (const float*)d_in[0];
  const float* known   = (const float*)d_in[1];
  const float* uf      = (const float*)d_in[2];
  const float* kf      = (const float*)d_in[3];
  const float* W1      = (const float*)d_in[4];
  const float* b1      = (const float*)d_in[5];
  const float* g1      = (const float*)d_in[6];
  const float* be1     = (const float*)d_in[7];
  const float* W2      = (const float*)d_in[8];
  const float* b2      = (const float*)d_in[9];
  const float* g2      = (const float*)d_in[10];
  const float* be2     = (const float*)d_in[11];

  char* ws = (char*)d_ws;
  unsigned short* X    = (unsigned short*)(ws);                 // kfb (8.4 MB) during gemm1, then y2 (33.5 MB)
  unsigned short* Y1   = (unsigned short*)(ws + 50331648);      // 33,554,432 (y1 raw)
  unsigned short* w1b  = (unsigned short*)(ws + 83886080);      // 196,608
  unsigned short* w2b  = (unsigned short*)(ws + 84082688);      // 131,072
  int*            widx = (int*)  (ws + 84213760);               // 786,432
  float*          wwgt = (float*)(ws + 85000192);               // 786,432
  float*          stats= (float*)(ws + 85786624);               // 8 KB
  float4*         kprep= (float4*)(ws + 85794816);              // 262,144
  float *sum1 = stats,        *sq1 = stats + 256;
  float *sum2 = stats + 512,  *sq2 = stats + 768;
  float* out = (float*)d_out;

  // prep: 181248 small items + 524288 kf->bf16 conversions = 705536 threads
  prep_kernel<<<2757, 256, 0, stream>>>(W1, W2, known, kf, w1b, w2b, stats, kprep, X);
  nn_kernel<<<dim3(128, 8), 512, 0, stream>>>(unknown, kprep, widx, wwgt);
  // gemm1: fused interp from bf16 kf (X region); batch->XCD swizzle
  gemm1_fused<<<1024, 256, 0, stream>>>(X, uf, widx, wwgt, w1b, b1, Y1, sum1, sq1);
  // gemm2: BN1 finalized in-kernel; fused BN1+ReLU on A; y2 -> X (overwrites kfb)
  gemm2_kernel<<<1024, 256, 0, stream>>>(Y1, w2b, b2, X, sum2, sq2, sum1, sq1, g1, be1);
  // final: BN2 finalized in-kernel; bf16 y2 -> fp32 d_out
  final_kernel<<<8192, 256, 0, stream>>>(X, out, sum2, sq2, g2, be2);
}

// Round 17
// 153.779 us; speedup vs baseline: 1.0195x; 1.0195x over previous
//
#include <hip/hip_runtime.h>

// ---------- problem constants ----------
#define BQ   8
#define NQ   8192      // unknown points per batch
#define MK   2048      // known points per batch
#define C1v  128
#define C2v  256
#define CIN  384
#define HH   256
#define MTOT (BQ*NQ)   // 65536

#define NCHUNK 8       // candidate chunks per nn block (= waves per block)
#define CHSZ   (MK/NCHUNK)   // 256 candidates per chunk

typedef __attribute__((ext_vector_type(8))) __bf16 bf16x8;
typedef __attribute__((ext_vector_type(4))) float f32x4;
typedef __attribute__((ext_vector_type(8))) unsigned short us8;
typedef __attribute__((ext_vector_type(4))) unsigned short us4;
typedef __attribute__((ext_vector_type(2))) unsigned short us2;

__device__ __forceinline__ unsigned short f2bf(float f) {
  unsigned int u = __builtin_bit_cast(unsigned int, f);
  u += 0x7fffu + ((u >> 16) & 1u);           // round-to-nearest-even
  return (unsigned short)(u >> 16);
}
__device__ __forceinline__ float bf2f(unsigned short h) {
  unsigned int u = ((unsigned int)h) << 16;
  return __builtin_bit_cast(float, u);
}

__device__ __forceinline__ void gload16(const void* g, void* l) {
  __builtin_amdgcn_global_load_lds((const __attribute__((address_space(1))) void*)g,
                                   (__attribute__((address_space(3))) void*)l, 16, 0, 0);
}

// packed f32->bf16 RNE convert (dst.lo = src0, dst.hi = src1)
__device__ __forceinline__ unsigned int cvtpk_bf16(float lo, float hi) {
  unsigned int r;
  asm("v_cvt_pk_bf16_f32 %0, %1, %2" : "=v"(r) : "v"(lo), "v"(hi));
  return r;
}

// score from a staged candidate: s = u.k - 0.5|k|^2  (kprep.w = -0.5|k|^2)
#define SCORE(k4) (fmaf((k4).x, ux, fmaf((k4).y, uy, (k4).z * uz)) + (k4).w)

// pack fp32 score + candidate index into one exactly-ordered f64 key:
// (double)s has 29 zero low mantissa bits; OR in (2047-j). Distinct fp32
// scores keep exact order; equal scores tie-break to smaller j (top_k rule).
__device__ __forceinline__ double packsd(float s, int negj) {
  unsigned long long u = __builtin_bit_cast(unsigned long long, (double)s)
                       | (unsigned long long)(unsigned int)negj;
  return __builtin_bit_cast(double, u);
}

// 5-op f64 top-3 insert (keys are all distinct): {s0,s1,s2} <- top3 of {s0,s1,s2,t}
#define INS3D(s0, s1, s2, t)                                  \
  do {                                                        \
    double _hi0 = fmax(s0, (t)), _lo0 = fmin(s0, (t));        \
    double _hi1 = fmax(s1, _lo0), _lo1 = fmin(s1, _lo0);      \
    s0 = _hi0; s1 = _hi1; s2 = fmax(s2, _lo1);                \
  } while (0)

// ---------- 1. prep: W->bf16, BN accum zero, kprep, kf->bf16 (kfb) ----------
__global__ __launch_bounds__(256)
void prep_kernel(const float* __restrict__ W1, const float* __restrict__ W2,
                 const float* __restrict__ known, const float* __restrict__ kf,
                 unsigned short* __restrict__ w1b, unsigned short* __restrict__ w2b,
                 float* __restrict__ stats, float4* __restrict__ kprep,
                 unsigned short* __restrict__ kfb) {
  int i = blockIdx.x * 256 + threadIdx.x;
  if (i < HH*CIN) w1b[i] = f2bf(W1[i]);
  else if (i < HH*CIN + HH*HH) w2b[i - HH*CIN] = f2bf(W2[i - HH*CIN]);
  int z = i - (HH*CIN + HH*HH);
  if (z >= 0 && z < 1024) stats[z] = 0.f;
  int z2 = i - (HH*CIN + HH*HH + 1024);
  if (z2 >= 0 && z2 < BQ*MK) {
    const float* kp = known + (size_t)z2 * 3;
    float x = kp[0], y = kp[1], zz = kp[2];
    kprep[z2] = make_float4(x, y, zz, -0.5f*(x*x + y*y + zz*zz));
  }
  int z3 = i - (HH*CIN + HH*HH + 1024 + BQ*MK);
  if (z3 >= 0 && z3 < (BQ*MK*C2v)/8) {
    const float4* src = (const float4*)(kf + (size_t)z3 * 8);
    float4 v0 = src[0], v1 = src[1];
    us8 o;
    o[0]=f2bf(v0.x); o[1]=f2bf(v0.y); o[2]=f2bf(v0.z); o[3]=f2bf(v0.w);
    o[4]=f2bf(v1.x); o[5]=f2bf(v1.y); o[6]=f2bf(v1.z); o[7]=f2bf(v1.w);
    *(us8*)(kfb + (size_t)z3 * 8) = o;
  }
}

// ---------- 2. three_nn: single pass, index-packed f64 keys (round-14 proven) ----------
__global__ __launch_bounds__(512)
void nn_kernel(const float* __restrict__ unknown, const float4* __restrict__ kprep,
               int* __restrict__ widx, float* __restrict__ wwgt) {
  __shared__ double pd[NCHUNK][64][3];      // per-chunk packed triples (12 KB)
  const int b = blockIdx.y;
  const int tid = threadIdx.x;
  const int wave = tid >> 6, lane = tid & 63;

  const int q = blockIdx.x * 64 + lane;
  const float* up = unknown + ((size_t)b * NQ + q) * 3;
  const float ux = up[0], uy = up[1], uz = up[2];
  const float nu = ux*ux + uy*uy + uz*uz;
  const int jbase = wave * CHSZ;
  // wave-uniform chunk pointer -> scalar-path candidate fetch
  const float4* cp = kprep + (b << 11) + __builtin_amdgcn_readfirstlane(jbase);

  // dual accumulator sets for ILP; keys are distinct so merge order is free
  double A0=-1e300, A1=-1e300, A2=-1e300;
  double B0=-1e300, B1=-1e300, B2=-1e300;
  #pragma unroll 4
  for (int j = 0; j < CHSZ; j += 2) {
    float4 ka = cp[j];
    float4 kc = cp[j+1];
    float sA = SCORE(ka);
    float sB = SCORE(kc);
    double da = packsd(sA, 2047 - (jbase + j));
    double db = packsd(sB, 2047 - (jbase + j + 1));
    INS3D(A0, A1, A2, da);
    INS3D(B0, B1, B2, db);
  }
  INS3D(A0, A1, A2, B0);
  INS3D(A0, A1, A2, B1);
  INS3D(A0, A1, A2, B2);
  pd[wave][lane][0] = A0; pd[wave][lane][1] = A1; pd[wave][lane][2] = A2;
  __syncthreads();

  if (tid < 64) {   // wave 0: lane == query; merge the 8 chunk triples
    double f0=-1e300, f1=-1e300, f2=-1e300;
    #pragma unroll
    for (int c = 0; c < NCHUNK; ++c) {
      INS3D(f0, f1, f2, pd[c][tid][0]);
      INS3D(f0, f1, f2, pd[c][tid][1]);
      INS3D(f0, f1, f2, pd[c][tid][2]);
    }
    unsigned long long u0 = __builtin_bit_cast(unsigned long long, f0);
    unsigned long long u1 = __builtin_bit_cast(unsigned long long, f1);
    unsigned long long u2 = __builtin_bit_cast(unsigned long long, f2);
    int x0 = 2047 - (int)(u0 & 2047ULL);
    int x1 = 2047 - (int)(u1 & 2047ULL);
    int x2 = 2047 - (int)(u2 & 2047ULL);
    // masking restores the exact fp32 score bits
    float s0 = (float)__builtin_bit_cast(double, u0 & ~2047ULL);
    float s1 = (float)__builtin_bit_cast(double, u1 & ~2047ULL);
    float s2 = (float)__builtin_bit_cast(double, u2 & ~2047ULL);
    float d0 = sqrtf(fmaxf(nu - 2.f*s0, 0.f)) + 1e-10f;
    float d1 = sqrtf(fmaxf(nu - 2.f*s1, 0.f)) + 1e-10f;
    float d2 = sqrtf(fmaxf(nu - 2.f*s2, 0.f)) + 1e-10f;
    float r0 = 1.f/d0, r1 = 1.f/d1, r2 = 1.f/d2;
    float rs = 1.f/(r0 + r1 + r2);
    size_t p = (size_t)b * NQ + q;
    widx[p*3+0] = x0;    widx[p*3+1] = x1;    widx[p*3+2] = x2;
    wwgt[p*3+0] = r0*rs; wwgt[p*3+1] = r1*rs; wwgt[p*3+2] = r2*rs;
  }
}

// ---------- 3. GEMM1 (fused interp): A built in-staging from bf16-kf gathers
// (3x16B per chunk) + uf concat. Straight load->lerp->ds_write per iteration
// (no cross-iteration prefetch state, no sched_barrier -- replay-stable).
// Block swizzle: batch = wid&7 -> all 128 blocks of a batch land on one XCD.
__global__ __launch_bounds__(256)
void gemm1_fused(const unsigned short* __restrict__ kfb, const float* __restrict__ uf,
                 const int* __restrict__ widx, const float* __restrict__ wwgt,
                 const unsigned short* __restrict__ Bw,
                 const float* __restrict__ bias,
                 unsigned short* __restrict__ Out,
                 float* __restrict__ gsum, float* __restrict__ gsq) {
  constexpr int K = CIN;
  __shared__ unsigned short As[128][64];   // 16 KB
  __shared__ unsigned short Bs[128][64];   // 16 KB
  const int tid  = threadIdx.x;
  const int lane = tid & 63;
  const int wave = tid >> 6;          // 0..3
  const int wid   = blockIdx.x;
  const int batch = wid & 7;          // -> XCD id
  const int inner = wid >> 3;         // 0..127 within batch
  const int bm = batch * 64 + (inner >> 1);
  const int bn = inner & 1;
  const int wm = wave >> 1, wn = wave & 1;

  // prologue: per-chunk gather byte-offsets + weights (chunk i -> fixed row/col)
  unsigned int voK0[4], voK1[4], voK2[4], voU[4];
  float w0r[4], w1r[4], w2r[4];
  #pragma unroll
  for (int i = 0; i < 4; ++i) {
    const int c = wave*64 + i*256 + lane;
    const int row = c >> 3;
    const int colK = (c & 7) * 16;     // byte offset within 512 B bf16 row
    const int colU = (c & 7) * 32;     // byte offset within 512 B fp32 row
    const int p = bm*128 + row;
    const int b = p >> 13;
    w0r[i] = wwgt[p*3+0]; w1r[i] = wwgt[p*3+1]; w2r[i] = wwgt[p*3+2];
    voK0[i] = ((unsigned)((b << 11) + widx[p*3+0]) << 9) + colK;
    voK1[i] = ((unsigned)((b << 11) + widx[p*3+1]) << 9) + colK;
    voK2[i] = ((unsigned)((b << 11) + widx[p*3+2]) << 9) + colK;
    voU[i]  = (unsigned)p * 512u + colU;
  }

  f32x4 acc[4][4];
  const f32x4 zero = {0.f, 0.f, 0.f, 0.f};
  #pragma unroll
  for (int m = 0; m < 4; ++m)
    #pragma unroll
    for (int n = 0; n < 4; ++n) acc[m][n] = zero;

  const char* kfbb = (const char*)kfb;
  const char* ufb  = (const char*)uf;

  #pragma unroll
  for (int t = 0; t < 6; ++t) {
    const int k0 = t * 64;
    // B-tile: async LDS-direct
    #pragma unroll
    for (int i = 0; i < 4; ++i) {
      const int cbase = wave*64 + i*256;
      const int c = cbase + lane;
      const int brow = c >> 3, bcol = (c & 7) * 8;
      gload16(Bw + ((size_t)(bn*128 + brow))*K + k0 + bcol, (unsigned short*)Bs + cbase*8);
    }
    // A-tile: load all gathers for this iteration, then lerp/convert/write
    if (t < 4) {
      us8 GA[4], GE[4], GG[4];
      #pragma unroll
      for (int i = 0; i < 4; ++i) {
        GA[i] = *(const us8*)(kfbb + voK0[i] + t*128);
        GE[i] = *(const us8*)(kfbb + voK1[i] + t*128);
        GG[i] = *(const us8*)(kfbb + voK2[i] + t*128);
      }
      #pragma unroll
      for (int i = 0; i < 4; ++i) {
        const int c = wave*64 + i*256 + lane;
        const float w0 = w0r[i], w1 = w1r[i], w2 = w2r[i];
        float r[8];
        #pragma unroll
        for (int j = 0; j < 8; ++j) {
          float fa = bf2f((unsigned short)GA[i][j]);
          float fe = bf2f((unsigned short)GE[i][j]);
          float fg = bf2f((unsigned short)GG[i][j]);
          r[j] = w0*fa + w1*fe + w2*fg;
        }
        uint4 ov;
        ov.x = cvtpk_bf16(r[0], r[1]);
        ov.y = cvtpk_bf16(r[2], r[3]);
        ov.z = cvtpk_bf16(r[4], r[5]);
        ov.w = cvtpk_bf16(r[6], r[7]);
        *(uint4*)((unsigned short*)As + (size_t)c*8) = ov;
      }
    } else {
      float4 U0[4], U1[4];
      #pragma unroll
      for (int i = 0; i < 4; ++i) {
        U0[i] = *(const float4*)(ufb + voU[i] + (t-4)*256);
        U1[i] = *(const float4*)(ufb + voU[i] + (t-4)*256 + 16);
      }
      #pragma unroll
      for (int i = 0; i < 4; ++i) {
        const int c = wave*64 + i*256 + lane;
        uint4 ov;
        ov.x = cvtpk_bf16(U0[i].x, U0[i].y);
        ov.y = cvtpk_bf16(U0[i].z, U0[i].w);
        ov.z = cvtpk_bf16(U1[i].x, U1[i].y);
        ov.w = cvtpk_bf16(U1[i].z, U1[i].w);
        *(uint4*)((unsigned short*)As + (size_t)c*8) = ov;
      }
    }
    __syncthreads();
    const int kq = (lane >> 4) * 8;
    #pragma unroll
    for (int kk = 0; kk < 64; kk += 32) {
      bf16x8 af[4], bfr[4];
      #pragma unroll
      for (int m = 0; m < 4; ++m)
        af[m] = *(const bf16x8*)&As[wm*64 + m*16 + (lane & 15)][kk + kq];
      #pragma unroll
      for (int n = 0; n < 4; ++n)
        bfr[n] = *(const bf16x8*)&Bs[wn*64 + n*16 + (lane & 15)][kk + kq];
      #pragma unroll
      for (int m = 0; m < 4; ++m)
        #pragma unroll
        for (int n = 0; n < 4; ++n)
          acc[m][n] = __builtin_amdgcn_mfma_f32_16x16x32_bf16(af[m], bfr[n], acc[m][n], 0, 0, 0);
    }
    __syncthreads();
  }

  // epilogue: bias, store bf16, per-channel sum/sumsq
  float* s_sum = (float*)&As[0][0];   // [2][128]
  float* s_sq  = s_sum + 256;         // [2][128]
  #pragma unroll
  for (int n = 0; n < 4; ++n) {
    const int cb   = wn*64 + n*16 + (lane & 15);
    const int gcol = bn*128 + cb;
    const float bv = bias[gcol];
    float sum = 0.f, sq = 0.f;
    #pragma unroll
    for (int m = 0; m < 4; ++m) {
      const size_t grow = (size_t)bm*128 + wm*64 + m*16 + (lane >> 4)*4;
      #pragma unroll
      for (int qq = 0; qq < 4; ++qq) {
        float y = acc[m][n][qq] + bv;
        sum += y; sq += y*y;
        Out[(grow+qq)*256 + gcol] = f2bf(y);
      }
    }
    sum += __shfl_xor(sum, 16, 64); sum += __shfl_xor(sum, 32, 64);
    sq  += __shfl_xor(sq , 16, 64); sq  += __shfl_xor(sq , 32, 64);
    if (lane < 16) { s_sum[wm*128 + cb] = sum; s_sq[wm*128 + cb] = sq; }
  }
  __syncthreads();
  if (tid < 128) {
    atomicAdd(&gsum[bn*128 + tid], s_sum[tid] + s_sum[128 + tid]);
    atomicAdd(&gsq [bn*128 + tid], s_sq [tid] + s_sq [128 + tid]);
  }
}

// ---------- 4. GEMM2: fused BN1+ReLU on A-load (scale/shift computed in preamble
// from raw sums), y2 bf16 out, + BN2 stats ----------
__global__ __launch_bounds__(256)
void gemm2_kernel(const unsigned short* __restrict__ A,     // y1 raw bf16
                  const unsigned short* __restrict__ Bw,    // W2 bf16
                  const float* __restrict__ bias,           // b2
                  unsigned short* __restrict__ Out,         // y2 bf16
                  float* __restrict__ gsum, float* __restrict__ gsq,     // BN2 accum
                  const float* __restrict__ gsum1, const float* __restrict__ gsq1,
                  const float* __restrict__ g1, const float* __restrict__ be1) {
  constexpr int K = HH;
  __shared__ unsigned short As[128][64];   // 16 KB
  __shared__ unsigned short Bs[128][64];   // 16 KB
  __shared__ float sc_l[HH], sh_l[HH];     // 2 KB
  const int tid  = threadIdx.x;
  const int lane = tid & 63;
  const int wave = tid >> 6;          // 0..3
  const int wid  = blockIdx.x;
  const int slot = wid & 15;
  const int bm = ((wid >> 4) << 3) | (slot & 7);
  const int bn = slot >> 3;
  const int wm = wave >> 1, wn = wave & 1;

  {  // BN1 finalize (redundant per block; replaces stats_fin dispatch)
    float mu  = gsum1[tid] * (1.f/65536.f);
    float var = gsq1[tid]  * (1.f/65536.f) - mu*mu;
    float sc  = g1[tid] * rsqrtf(var + 1e-5f);
    sc_l[tid] = sc;
    sh_l[tid] = be1[tid] - mu*sc;
  }
  __syncthreads();

  f32x4 acc[4][4];
  const f32x4 zero = {0.f, 0.f, 0.f, 0.f};
  #pragma unroll
  for (int m = 0; m < 4; ++m)
    #pragma unroll
    for (int n = 0; n < 4; ++n) acc[m][n] = zero;

  for (int k0 = 0; k0 < K; k0 += 64) {
    #pragma unroll
    for (int i = 0; i < 4; ++i) {
      const int cbase = wave*64 + i*256;          // wave-uniform chunk base
      const int c = cbase + lane;                 // per-lane chunk (16 B)
      const int row = c >> 3, col = (c & 7) * 8;
      gload16(Bw + ((size_t)(bn*128 + row))*K + k0 + col, (unsigned short*)Bs + cbase*8);
      us8 v = *(const us8*)(A + ((size_t)(bm*128 + row))*K + k0 + col);
      us8 o;
      #pragma unroll
      for (int j = 0; j < 8; ++j) {
        float y = fmaxf(fmaf(bf2f(v[j]), sc_l[k0+col+j], sh_l[k0+col+j]), 0.f);
        o[j] = f2bf(y);
      }
      *(us8*)((unsigned short*)As + cbase*8 + lane*8) = o;
    }
    __syncthreads();
    const int kq = (lane >> 4) * 8;
    #pragma unroll
    for (int kk = 0; kk < 64; kk += 32) {
      bf16x8 af[4], bfr[4];
      #pragma unroll
      for (int m = 0; m < 4; ++m)
        af[m] = *(const bf16x8*)&As[wm*64 + m*16 + (lane & 15)][kk + kq];
      #pragma unroll
      for (int n = 0; n < 4; ++n)
        bfr[n] = *(const bf16x8*)&Bs[wn*64 + n*16 + (lane & 15)][kk + kq];
      #pragma unroll
      for (int m = 0; m < 4; ++m)
        #pragma unroll
        for (int n = 0; n < 4; ++n)
          acc[m][n] = __builtin_amdgcn_mfma_f32_16x16x32_bf16(af[m], bfr[n], acc[m][n], 0, 0, 0);
    }
    __syncthreads();
  }

  // epilogue: bias, store bf16 y2, per-channel sum/sumsq
  float* s_sum = (float*)&As[0][0];   // [2][128]
  float* s_sq  = s_sum + 256;         // [2][128]
  #pragma unroll
  for (int n = 0; n < 4; ++n) {
    const int cb   = wn*64 + n*16 + (lane & 15);
    const int gcol = bn*128 + cb;
    const float bv = bias[gcol];
    float sum = 0.f, sq = 0.f;
    #pragma unroll
    for (int m = 0; m < 4; ++m) {
      const size_t grow = (size_t)bm*128 + wm*64 + m*16 + (lane >> 4)*4;
      #pragma unroll
      for (int qq = 0; qq < 4; ++qq) {
        float y = acc[m][n][qq] + bv;
        sum += y; sq += y*y;
        Out[(grow+qq)*256 + gcol] = f2bf(y);
      }
    }
    sum += __shfl_xor(sum, 16, 64); sum += __shfl_xor(sum, 32, 64);
    sq  += __shfl_xor(sq , 16, 64); sq  += __shfl_xor(sq , 32, 64);
    if (lane < 16) { s_sum[wm*128 + cb] = sum; s_sq[wm*128 + cb] = sq; }
  }
  __syncthreads();
  if (tid < 128) {
    atomicAdd(&gsum[bn*128 + tid], s_sum[tid] + s_sum[128 + tid]);
    atomicAdd(&gsq [bn*128 + tid], s_sq [tid] + s_sq [128 + tid]);
  }
}

// ---------- 5. final BN2+ReLU: bf16 y2 -> fp32 d_out (scale/shift in preamble) ----------
__global__ __launch_bounds__(256)
void final_kernel(const unsigned short* __restrict__ Y2, float* __restrict__ Out,
                  const float* __restrict__ gsum, const float* __restrict__ gsq,
                  const float* __restrict__ g2, const float* __restrict__ be2) {
  __shared__ float sc[256], sh[256];
  {  // BN2 finalize (redundant per block; replaces stats_fin dispatch)
    float mu  = gsum[threadIdx.x] * (1.f/65536.f);
    float var = gsq[threadIdx.x]  * (1.f/65536.f) - mu*mu;
    float scv = g2[threadIdx.x] * rsqrtf(var + 1e-5f);
    sc[threadIdx.x] = scv;
    sh[threadIdx.x] = be2[threadIdx.x] - mu*scv;
  }
  __syncthreads();
  size_t i = ((size_t)blockIdx.x * 256 + threadIdx.x) * 8;
  int c0 = (int)(i & 255);
  us8 v = *(const us8*)(Y2 + i);
  float4 o1, o2;
  o1.x = fmaxf(fmaf(bf2f(v[0]), sc[c0+0], sh[c0+0]), 0.f);
  o1.y = fmaxf(fmaf(bf2f(v[1]), sc[c0+1], sh[c0+1]), 0.f);
  o1.z = fmaxf(fmaf(bf2f(v[2]), sc[c0+2], sh[c0+2]), 0.f);
  o1.w = fmaxf(fmaf(bf2f(v[3]), sc[c0+3], sh[c0+3]), 0.f);
  o2.x = fmaxf(fmaf(bf2f(v[4]), sc[c0+4], sh[c0+4]), 0.f);
  o2.y = fmaxf(fmaf(bf2f(v[5]), sc[c0+5], sh[c0+5]), 0.f);
  o2.z = fmaxf(fmaf(bf2f(v[6]), sc[c0+6], sh[c0+6]), 0.f);
  o2.w = fmaxf(fmaf(bf2f(v[7]), sc[c0+7], sh[c0+7]), 0.f);
  *(float4*)(Out + i)     = o1;
  *(float4*)(Out + i + 4) = o2;
}

// ---------- launch ----------
extern "C" void kernel_launch(void* const* d_in, const int* in_sizes, int n_in,
                              void* d_out, int out_size, void* d_ws, size_t ws_size,
                              hipStream_t stream) {
  const float* unknown = (const float*)d_in[0];
  const float* known   = (const float*)d_in[1];
  const float* uf      = (const float*)d_in[2];
  const float* kf      = (const float*)d_in[3];
  const float* W1      = (const float*)d_in[4];
  const float* b1      = (const float*)d_in[5];
  const float* g1      = (const float*)d_in[6];
  const float* be1     = (const float*)d_in[7];
  const float* W2      = (const float*)d_in[8];
  const float* b2      = (const float*)d_in[9];
  const float* g2      = (const float*)d_in[10];
  const float* be2     = (const float*)d_in[11];

  char* ws = (char*)d_ws;
  unsigned short* X    = (unsigned short*)(ws);                 // kfb (8.4 MB) during gemm1, then y2 (33.5 MB)
  unsigned short* Y1   = (unsigned short*)(ws + 50331648);      // 33,554,432 (y1 raw)
  unsigned short* w1b  = (unsigned short*)(ws + 83886080);      // 196,608
  unsigned short* w2b  = (unsigned short*)(ws + 84082688);      // 131,072
  int*            widx = (int*)  (ws + 84213760);               // 786,432
  float*          wwgt = (float*)(ws + 85000192);               // 786,432
  float*          stats= (float*)(ws + 85786624);               // 8 KB
  float4*         kprep= (float4*)(ws + 85794816);              // 262,144
  float *sum1 = stats,        *sq1 = stats + 256;
  float *sum2 = stats + 512,  *sq2 = stats + 768;
  float* out = (float*)d_out;

  // prep: 181248 small items + 524288 kf->bf16 conversions = 705536 threads
  prep_kernel<<<2757, 256, 0, stream>>>(W1, W2, known, kf, w1b, w2b, stats, kprep, X);
  nn_kernel<<<dim3(128, 8), 512, 0, stream>>>(unknown, kprep, widx, wwgt);
  // gemm1: fused interp from bf16 kf (X region); batch->XCD swizzle
  gemm1_fused<<<1024, 256, 0, stream>>>(X, uf, widx, wwgt, w1b, b1, Y1, sum1, sq1);
  // gemm2: BN1 finalized in-kernel; fused BN1+ReLU on A; y2 -> X (overwrites kfb)
  gemm2_kernel<<<1024, 256, 0, stream>>>(Y1, w2b, b2, X, sum2, sq2, sum1, sq1, g1, be1);
  // final: BN2 finalized in-kernel; bf16 y2 -> fp32 d_out
  final_kernel<<<8192, 256, 0, stream>>>(X, out, sum2, sq2, g2, be2);
}

// Round 18
// 151.958 us; speedup vs baseline: 1.0317x; 1.0120x over previous
//
#include <hip/hip_runtime.h>

// ---------- problem constants ----------
#define BQ   8
#define NQ   8192      // unknown points per batch
#define MK   2048      // known points per batch
#define C1v  128
#define C2v  256
#define CIN  384
#define HH   256
#define MTOT (BQ*NQ)   // 65536

#define NCHUNK 8       // candidate chunks per nn block (= waves per block)
#define CHSZ   (MK/NCHUNK)   // 256 candidates per chunk

typedef __attribute__((ext_vector_type(8))) __bf16 bf16x8;
typedef __attribute__((ext_vector_type(4))) float f32x4;
typedef __attribute__((ext_vector_type(8))) unsigned short us8;
typedef __attribute__((ext_vector_type(4))) unsigned short us4;
typedef __attribute__((ext_vector_type(2))) unsigned short us2;

__device__ __forceinline__ unsigned short f2bf(float f) {
  unsigned int u = __builtin_bit_cast(unsigned int, f);
  u += 0x7fffu + ((u >> 16) & 1u);           // round-to-nearest-even
  return (unsigned short)(u >> 16);
}
__device__ __forceinline__ float bf2f(unsigned short h) {
  unsigned int u = ((unsigned int)h) << 16;
  return __builtin_bit_cast(float, u);
}

__device__ __forceinline__ void gload16(const void* g, void* l) {
  __builtin_amdgcn_global_load_lds((const __attribute__((address_space(1))) void*)g,
                                   (__attribute__((address_space(3))) void*)l, 16, 0, 0);
}

// packed f32->bf16 RNE convert (dst.lo = src0, dst.hi = src1)
__device__ __forceinline__ unsigned int cvtpk_bf16(float lo, float hi) {
  unsigned int r;
  asm("v_cvt_pk_bf16_f32 %0, %1, %2" : "=v"(r) : "v"(lo), "v"(hi));
  return r;
}

// score from a staged candidate: s = u.k - 0.5|k|^2  (kprep.w = -0.5|k|^2)
#define SCORE(k4) (fmaf((k4).x, ux, fmaf((k4).y, uy, (k4).z * uz)) + (k4).w)

// pack fp32 score + candidate index into one exactly-ordered f64 key:
// (double)s has 29 zero low mantissa bits; OR in (2047-j). Distinct fp32
// scores keep exact order; equal scores tie-break to smaller j (top_k rule).
__device__ __forceinline__ double packsd(float s, int negj) {
  unsigned long long u = __builtin_bit_cast(unsigned long long, (double)s)
                       | (unsigned long long)(unsigned int)negj;
  return __builtin_bit_cast(double, u);
}

// 5-op f64 top-3 insert (keys are all distinct): {s0,s1,s2} <- top3 of {s0,s1,s2,t}
#define INS3D(s0, s1, s2, t)                                  \
  do {                                                        \
    double _hi0 = fmax(s0, (t)), _lo0 = fmin(s0, (t));        \
    double _hi1 = fmax(s1, _lo0), _lo1 = fmin(s1, _lo0);      \
    s0 = _hi0; s1 = _hi1; s2 = fmax(s2, _lo1);                \
  } while (0)

// ---------- 1. prep: W->bf16, BN accum zero, kprep, kf->bf16 (kfb) ----------
__global__ __launch_bounds__(256)
void prep_kernel(const float* __restrict__ W1, const float* __restrict__ W2,
                 const float* __restrict__ known, const float* __restrict__ kf,
                 unsigned short* __restrict__ w1b, unsigned short* __restrict__ w2b,
                 float* __restrict__ stats, float4* __restrict__ kprep,
                 unsigned short* __restrict__ kfb) {
  int i = blockIdx.x * 256 + threadIdx.x;
  if (i < HH*CIN) w1b[i] = f2bf(W1[i]);
  else if (i < HH*CIN + HH*HH) w2b[i - HH*CIN] = f2bf(W2[i - HH*CIN]);
  int z = i - (HH*CIN + HH*HH);
  if (z >= 0 && z < 1024) stats[z] = 0.f;
  int z2 = i - (HH*CIN + HH*HH + 1024);
  if (z2 >= 0 && z2 < BQ*MK) {
    const float* kp = known + (size_t)z2 * 3;
    float x = kp[0], y = kp[1], zz = kp[2];
    kprep[z2] = make_float4(x, y, zz, -0.5f*(x*x + y*y + zz*zz));
  }
  int z3 = i - (HH*CIN + HH*HH + 1024 + BQ*MK);
  if (z3 >= 0 && z3 < (BQ*MK*C2v)/8) {
    const float4* src = (const float4*)(kf + (size_t)z3 * 8);
    float4 v0 = src[0], v1 = src[1];
    us8 o;
    o[0]=f2bf(v0.x); o[1]=f2bf(v0.y); o[2]=f2bf(v0.z); o[3]=f2bf(v0.w);
    o[4]=f2bf(v1.x); o[5]=f2bf(v1.y); o[6]=f2bf(v1.z); o[7]=f2bf(v1.w);
    *(us8*)(kfb + (size_t)z3 * 8) = o;
  }
}

// ---------- 2. three_nn: single pass, index-packed f64 keys (round-14 proven) ----------
__global__ __launch_bounds__(512)
void nn_kernel(const float* __restrict__ unknown, const float4* __restrict__ kprep,
               int* __restrict__ widx, float* __restrict__ wwgt) {
  __shared__ double pd[NCHUNK][64][3];      // per-chunk packed triples (12 KB)
  const int b = blockIdx.y;
  const int tid = threadIdx.x;
  const int wave = tid >> 6, lane = tid & 63;

  const int q = blockIdx.x * 64 + lane;
  const float* up = unknown + ((size_t)b * NQ + q) * 3;
  const float ux = up[0], uy = up[1], uz = up[2];
  const float nu = ux*ux + uy*uy + uz*uz;
  const int jbase = wave * CHSZ;
  // wave-uniform chunk pointer -> scalar-path candidate fetch
  const float4* cp = kprep + (b << 11) + __builtin_amdgcn_readfirstlane(jbase);

  // dual accumulator sets for ILP; keys are distinct so merge order is free
  double A0=-1e300, A1=-1e300, A2=-1e300;
  double B0=-1e300, B1=-1e300, B2=-1e300;
  #pragma unroll 4
  for (int j = 0; j < CHSZ; j += 2) {
    float4 ka = cp[j];
    float4 kc = cp[j+1];
    float sA = SCORE(ka);
    float sB = SCORE(kc);
    double da = packsd(sA, 2047 - (jbase + j));
    double db = packsd(sB, 2047 - (jbase + j + 1));
    INS3D(A0, A1, A2, da);
    INS3D(B0, B1, B2, db);
  }
  INS3D(A0, A1, A2, B0);
  INS3D(A0, A1, A2, B1);
  INS3D(A0, A1, A2, B2);
  pd[wave][lane][0] = A0; pd[wave][lane][1] = A1; pd[wave][lane][2] = A2;
  __syncthreads();

  if (tid < 64) {   // wave 0: lane == query; merge the 8 chunk triples
    double f0=-1e300, f1=-1e300, f2=-1e300;
    #pragma unroll
    for (int c = 0; c < NCHUNK; ++c) {
      INS3D(f0, f1, f2, pd[c][tid][0]);
      INS3D(f0, f1, f2, pd[c][tid][1]);
      INS3D(f0, f1, f2, pd[c][tid][2]);
    }
    unsigned long long u0 = __builtin_bit_cast(unsigned long long, f0);
    unsigned long long u1 = __builtin_bit_cast(unsigned long long, f1);
    unsigned long long u2 = __builtin_bit_cast(unsigned long long, f2);
    int x0 = 2047 - (int)(u0 & 2047ULL);
    int x1 = 2047 - (int)(u1 & 2047ULL);
    int x2 = 2047 - (int)(u2 & 2047ULL);
    // masking restores the exact fp32 score bits
    float s0 = (float)__builtin_bit_cast(double, u0 & ~2047ULL);
    float s1 = (float)__builtin_bit_cast(double, u1 & ~2047ULL);
    float s2 = (float)__builtin_bit_cast(double, u2 & ~2047ULL);
    float d0 = sqrtf(fmaxf(nu - 2.f*s0, 0.f)) + 1e-10f;
    float d1 = sqrtf(fmaxf(nu - 2.f*s1, 0.f)) + 1e-10f;
    float d2 = sqrtf(fmaxf(nu - 2.f*s2, 0.f)) + 1e-10f;
    float r0 = 1.f/d0, r1 = 1.f/d1, r2 = 1.f/d2;
    float rs = 1.f/(r0 + r1 + r2);
    size_t p = (size_t)b * NQ + q;
    widx[p*3+0] = x0;    widx[p*3+1] = x1;    widx[p*3+2] = x2;
    wwgt[p*3+0] = r0*rs; wwgt[p*3+1] = r1*rs; wwgt[p*3+2] = r2*rs;
  }
}

// ---------- 3. GEMM1 (fused interp), 8 waves/block for gather-latency hiding.
// A built in-staging from bf16-kf gathers (3x16B per chunk, 2 chunks/thread)
// + uf concat. Straight load->lerp->ds_write (no cross-iteration state).
// Block swizzle: batch = wid&7 -> all 128 blocks of a batch land on one XCD.
__global__ __launch_bounds__(512)
void gemm1_fused(const unsigned short* __restrict__ kfb, const float* __restrict__ uf,
                 const int* __restrict__ widx, const float* __restrict__ wwgt,
                 const unsigned short* __restrict__ Bw,
                 const float* __restrict__ bias,
                 unsigned short* __restrict__ Out,
                 float* __restrict__ gsum, float* __restrict__ gsq) {
  constexpr int K = CIN;
  __shared__ unsigned short As[128][64];   // 16 KB
  __shared__ unsigned short Bs[128][64];   // 16 KB
  const int tid  = threadIdx.x;
  const int lane = tid & 63;
  const int wave = tid >> 6;          // 0..7
  const int wid   = blockIdx.x;
  const int batch = wid & 7;          // -> XCD id
  const int inner = wid >> 3;         // 0..127 within batch
  const int bm = batch * 64 + (inner >> 1);
  const int bn = inner & 1;
  const int wm = wave >> 1;           // 0..3: 32-row slice
  const int wn = wave & 1;            // 0..1: 64-col slice

  // prologue: per-chunk gather byte-offsets + weights (chunk i -> fixed row/col)
  unsigned int voK0[2], voK1[2], voK2[2], voU[2];
  float w0r[2], w1r[2], w2r[2];
  #pragma unroll
  for (int i = 0; i < 2; ++i) {
    const int c = i*512 + tid;
    const int row = c >> 3;
    const int colK = (c & 7) * 16;     // byte offset within 512 B bf16 row
    const int colU = (c & 7) * 32;     // byte offset within 512 B fp32 row
    const int p = bm*128 + row;
    const int b = p >> 13;
    w0r[i] = wwgt[p*3+0]; w1r[i] = wwgt[p*3+1]; w2r[i] = wwgt[p*3+2];
    voK0[i] = ((unsigned)((b << 11) + widx[p*3+0]) << 9) + colK;
    voK1[i] = ((unsigned)((b << 11) + widx[p*3+1]) << 9) + colK;
    voK2[i] = ((unsigned)((b << 11) + widx[p*3+2]) << 9) + colK;
    voU[i]  = (unsigned)p * 512u + colU;
  }

  f32x4 acc[2][4];
  const f32x4 zero = {0.f, 0.f, 0.f, 0.f};
  #pragma unroll
  for (int m = 0; m < 2; ++m)
    #pragma unroll
    for (int n = 0; n < 4; ++n) acc[m][n] = zero;

  const char* kfbb = (const char*)kfb;
  const char* ufb  = (const char*)uf;

  #pragma unroll
  for (int t = 0; t < 6; ++t) {
    const int k0 = t * 64;
    // B-tile: async LDS-direct (2 chunks per thread via wave-uniform bases)
    #pragma unroll
    for (int i = 0; i < 2; ++i) {
      const int cbase = i*512 + wave*64;
      const int c = cbase + lane;
      const int brow = c >> 3, bcol = (c & 7) * 8;
      gload16(Bw + ((size_t)(bn*128 + brow))*K + k0 + bcol, (unsigned short*)Bs + cbase*8);
    }
    // A-tile: load all gathers for this iteration, then lerp/convert/write
    if (t < 4) {
      us8 GA[2], GE[2], GG[2];
      #pragma unroll
      for (int i = 0; i < 2; ++i) {
        GA[i] = *(const us8*)(kfbb + voK0[i] + t*128);
        GE[i] = *(const us8*)(kfbb + voK1[i] + t*128);
        GG[i] = *(const us8*)(kfbb + voK2[i] + t*128);
      }
      #pragma unroll
      for (int i = 0; i < 2; ++i) {
        const int c = i*512 + tid;
        const float w0 = w0r[i], w1 = w1r[i], w2 = w2r[i];
        float r[8];
        #pragma unroll
        for (int j = 0; j < 8; ++j) {
          float fa = bf2f((unsigned short)GA[i][j]);
          float fe = bf2f((unsigned short)GE[i][j]);
          float fg = bf2f((unsigned short)GG[i][j]);
          r[j] = w0*fa + w1*fe + w2*fg;
        }
        uint4 ov;
        ov.x = cvtpk_bf16(r[0], r[1]);
        ov.y = cvtpk_bf16(r[2], r[3]);
        ov.z = cvtpk_bf16(r[4], r[5]);
        ov.w = cvtpk_bf16(r[6], r[7]);
        *(uint4*)((unsigned short*)As + (size_t)c*8) = ov;
      }
    } else {
      float4 U0[2], U1[2];
      #pragma unroll
      for (int i = 0; i < 2; ++i) {
        U0[i] = *(const float4*)(ufb + voU[i] + (t-4)*256);
        U1[i] = *(const float4*)(ufb + voU[i] + (t-4)*256 + 16);
      }
      #pragma unroll
      for (int i = 0; i < 2; ++i) {
        const int c = i*512 + tid;
        uint4 ov;
        ov.x = cvtpk_bf16(U0[i].x, U0[i].y);
        ov.y = cvtpk_bf16(U0[i].z, U0[i].w);
        ov.z = cvtpk_bf16(U1[i].x, U1[i].y);
        ov.w = cvtpk_bf16(U1[i].z, U1[i].w);
        *(uint4*)((unsigned short*)As + (size_t)c*8) = ov;
      }
    }
    __syncthreads();
    const int kq = (lane >> 4) * 8;
    #pragma unroll
    for (int kk = 0; kk < 64; kk += 32) {
      bf16x8 af[2], bfr[4];
      #pragma unroll
      for (int m = 0; m < 2; ++m)
        af[m] = *(const bf16x8*)&As[wm*32 + m*16 + (lane & 15)][kk + kq];
      #pragma unroll
      for (int n = 0; n < 4; ++n)
        bfr[n] = *(const bf16x8*)&Bs[wn*64 + n*16 + (lane & 15)][kk + kq];
      #pragma unroll
      for (int m = 0; m < 2; ++m)
        #pragma unroll
        for (int n = 0; n < 4; ++n)
          acc[m][n] = __builtin_amdgcn_mfma_f32_16x16x32_bf16(af[m], bfr[n], acc[m][n], 0, 0, 0);
    }
    __syncthreads();
  }

  // epilogue: bias, store bf16, per-channel sum/sumsq (per-wm partials)
  float* s_sum = (float*)&As[0][0];   // [4][128]
  float* s_sq  = s_sum + 512;         // [4][128]
  #pragma unroll
  for (int n = 0; n < 4; ++n) {
    const int cb   = wn*64 + n*16 + (lane & 15);
    const int gcol = bn*128 + cb;
    const float bv = bias[gcol];
    float sum = 0.f, sq = 0.f;
    #pragma unroll
    for (int m = 0; m < 2; ++m) {
      const size_t grow = (size_t)bm*128 + wm*32 + m*16 + (lane >> 4)*4;
      #pragma unroll
      for (int qq = 0; qq < 4; ++qq) {
        float y = acc[m][n][qq] + bv;
        sum += y; sq += y*y;
        Out[(grow+qq)*256 + gcol] = f2bf(y);
      }
    }
    sum += __shfl_xor(sum, 16, 64); sum += __shfl_xor(sum, 32, 64);
    sq  += __shfl_xor(sq , 16, 64); sq  += __shfl_xor(sq , 32, 64);
    if (lane < 16) { s_sum[wm*128 + cb] = sum; s_sq[wm*128 + cb] = sq; }
  }
  __syncthreads();
  if (tid < 128) {
    float ts = s_sum[tid] + s_sum[128+tid] + s_sum[256+tid] + s_sum[384+tid];
    float tq = s_sq [tid] + s_sq [128+tid] + s_sq [256+tid] + s_sq [384+tid];
    atomicAdd(&gsum[bn*128 + tid], ts);
    atomicAdd(&gsq [bn*128 + tid], tq);
  }
}

// ---------- 4. GEMM2: fused BN1+ReLU on A-load (scale/shift computed in preamble
// from raw sums), y2 bf16 out, + BN2 stats ----------
__global__ __launch_bounds__(256)
void gemm2_kernel(const unsigned short* __restrict__ A,     // y1 raw bf16
                  const unsigned short* __restrict__ Bw,    // W2 bf16
                  const float* __restrict__ bias,           // b2
                  unsigned short* __restrict__ Out,         // y2 bf16
                  float* __restrict__ gsum, float* __restrict__ gsq,     // BN2 accum
                  const float* __restrict__ gsum1, const float* __restrict__ gsq1,
                  const float* __restrict__ g1, const float* __restrict__ be1) {
  constexpr int K = HH;
  __shared__ unsigned short As[128][64];   // 16 KB
  __shared__ unsigned short Bs[128][64];   // 16 KB
  __shared__ float sc_l[HH], sh_l[HH];     // 2 KB
  const int tid  = threadIdx.x;
  const int lane = tid & 63;
  const int wave = tid >> 6;          // 0..3
  const int wid  = blockIdx.x;
  const int slot = wid & 15;
  const int bm = ((wid >> 4) << 3) | (slot & 7);
  const int bn = slot >> 3;
  const int wm = wave >> 1, wn = wave & 1;

  {  // BN1 finalize (redundant per block; replaces stats_fin dispatch)
    float mu  = gsum1[tid] * (1.f/65536.f);
    float var = gsq1[tid]  * (1.f/65536.f) - mu*mu;
    float sc  = g1[tid] * rsqrtf(var + 1e-5f);
    sc_l[tid] = sc;
    sh_l[tid] = be1[tid] - mu*sc;
  }
  __syncthreads();

  f32x4 acc[4][4];
  const f32x4 zero = {0.f, 0.f, 0.f, 0.f};
  #pragma unroll
  for (int m = 0; m < 4; ++m)
    #pragma unroll
    for (int n = 0; n < 4; ++n) acc[m][n] = zero;

  for (int k0 = 0; k0 < K; k0 += 64) {
    #pragma unroll
    for (int i = 0; i < 4; ++i) {
      const int cbase = wave*64 + i*256;          // wave-uniform chunk base
      const int c = cbase + lane;                 // per-lane chunk (16 B)
      const int row = c >> 3, col = (c & 7) * 8;
      gload16(Bw + ((size_t)(bn*128 + row))*K + k0 + col, (unsigned short*)Bs + cbase*8);
      us8 v = *(const us8*)(A + ((size_t)(bm*128 + row))*K + k0 + col);
      us8 o;
      #pragma unroll
      for (int j = 0; j < 8; ++j) {
        float y = fmaxf(fmaf(bf2f(v[j]), sc_l[k0+col+j], sh_l[k0+col+j]), 0.f);
        o[j] = f2bf(y);
      }
      *(us8*)((unsigned short*)As + cbase*8 + lane*8) = o;
    }
    __syncthreads();
    const int kq = (lane >> 4) * 8;
    #pragma unroll
    for (int kk = 0; kk < 64; kk += 32) {
      bf16x8 af[4], bfr[4];
      #pragma unroll
      for (int m = 0; m < 4; ++m)
        af[m] = *(const bf16x8*)&As[wm*64 + m*16 + (lane & 15)][kk + kq];
      #pragma unroll
      for (int n = 0; n < 4; ++n)
        bfr[n] = *(const bf16x8*)&Bs[wn*64 + n*16 + (lane & 15)][kk + kq];
      #pragma unroll
      for (int m = 0; m < 4; ++m)
        #pragma unroll
        for (int n = 0; n < 4; ++n)
          acc[m][n] = __builtin_amdgcn_mfma_f32_16x16x32_bf16(af[m], bfr[n], acc[m][n], 0, 0, 0);
    }
    __syncthreads();
  }

  // epilogue: bias, store bf16 y2, per-channel sum/sumsq
  float* s_sum = (float*)&As[0][0];   // [2][128]
  float* s_sq  = s_sum + 256;         // [2][128]
  #pragma unroll
  for (int n = 0; n < 4; ++n) {
    const int cb   = wn*64 + n*16 + (lane & 15);
    const int gcol = bn*128 + cb;
    const float bv = bias[gcol];
    float sum = 0.f, sq = 0.f;
    #pragma unroll
    for (int m = 0; m < 4; ++m) {
      const size_t grow = (size_t)bm*128 + wm*64 + m*16 + (lane >> 4)*4;
      #pragma unroll
      for (int qq = 0; qq < 4; ++qq) {
        float y = acc[m][n][qq] + bv;
        sum += y; sq += y*y;
        Out[(grow+qq)*256 + gcol] = f2bf(y);
      }
    }
    sum += __shfl_xor(sum, 16, 64); sum += __shfl_xor(sum, 32, 64);
    sq  += __shfl_xor(sq , 16, 64); sq  += __shfl_xor(sq , 32, 64);
    if (lane < 16) { s_sum[wm*128 + cb] = sum; s_sq[wm*128 + cb] = sq; }
  }
  __syncthreads();
  if (tid < 128) {
    atomicAdd(&gsum[bn*128 + tid], s_sum[tid] + s_sum[128 + tid]);
    atomicAdd(&gsq [bn*128 + tid], s_sq [tid] + s_sq [128 + tid]);
  }
}

// ---------- 5. final BN2+ReLU: bf16 y2 -> fp32 d_out (scale/shift in preamble) ----------
__global__ __launch_bounds__(256)
void final_kernel(const unsigned short* __restrict__ Y2, float* __restrict__ Out,
                  const float* __restrict__ gsum, const float* __restrict__ gsq,
                  const float* __restrict__ g2, const float* __restrict__ be2) {
  __shared__ float sc[256], sh[256];
  {  // BN2 finalize (redundant per block; replaces stats_fin dispatch)
    float mu  = gsum[threadIdx.x] * (1.f/65536.f);
    float var = gsq[threadIdx.x]  * (1.f/65536.f) - mu*mu;
    float scv = g2[threadIdx.x] * rsqrtf(var + 1e-5f);
    sc[threadIdx.x] = scv;
    sh[threadIdx.x] = be2[threadIdx.x] - mu*scv;
  }
  __syncthreads();
  size_t i = ((size_t)blockIdx.x * 256 + threadIdx.x) * 8;
  int c0 = (int)(i & 255);
  us8 v = *(const us8*)(Y2 + i);
  float4 o1, o2;
  o1.x = fmaxf(fmaf(bf2f(v[0]), sc[c0+0], sh[c0+0]), 0.f);
  o1.y = fmaxf(fmaf(bf2f(v[1]), sc[c0+1], sh[c0+1]), 0.f);
  o1.z = fmaxf(fmaf(bf2f(v[2]), sc[c0+2], sh[c0+2]), 0.f);
  o1.w = fmaxf(fmaf(bf2f(v[3]), sc[c0+3], sh[c0+3]), 0.f);
  o2.x = fmaxf(fmaf(bf2f(v[4]), sc[c0+4], sh[c0+4]), 0.f);
  o2.y = fmaxf(fmaf(bf2f(v[5]), sc[c0+5], sh[c0+5]), 0.f);
  o2.z = fmaxf(fmaf(bf2f(v[6]), sc[c0+6], sh[c0+6]), 0.f);
  o2.w = fmaxf(fmaf(bf2f(v[7]), sc[c0+7], sh[c0+7]), 0.f);
  *(float4*)(Out + i)     = o1;
  *(float4*)(Out + i + 4) = o2;
}

// ---------- launch ----------
extern "C" void kernel_launch(void* const* d_in, const int* in_sizes, int n_in,
                              void* d_out, int out_size, void* d_ws, size_t ws_size,
                              hipStream_t stream) {
  const float* unknown = (const float*)d_in[0];
  const float* known   = (const float*)d_in[1];
  const float* uf      = (const float*)d_in[2];
  const float* kf      = (const float*)d_in[3];
  const float* W1      = (const float*)d_in[4];
  const float* b1      = (const float*)d_in[5];
  const float* g1      = (const float*)d_in[6];
  const float* be1     = (const float*)d_in[7];
  const float* W2      = (const float*)d_in[8];
  const float* b2      = (const float*)d_in[9];
  const float* g2      = (const float*)d_in[10];
  const float* be2     = (const float*)d_in[11];

  char* ws = (char*)d_ws;
  unsigned short* X    = (unsigned short*)(ws);                 // kfb (8.4 MB) during gemm1, then y2 (33.5 MB)
  unsigned short* Y1   = (unsigned short*)(ws + 50331648);      // 33,554,432 (y1 raw)
  unsigned short* w1b  = (unsigned short*)(ws + 83886080);      // 196,608
  unsigned short* w2b  = (unsigned short*)(ws + 84082688);      // 131,072
  int*            widx = (int*)  (ws + 84213760);               // 786,432
  float*          wwgt = (float*)(ws + 85000192);               // 786,432
  float*          stats= (float*)(ws + 85786624);               // 8 KB
  float4*         kprep= (float4*)(ws + 85794816);              // 262,144
  float *sum1 = stats,        *sq1 = stats + 256;
  float *sum2 = stats + 512,  *sq2 = stats + 768;
  float* out = (float*)d_out;

  // prep: 181248 small items + 524288 kf->bf16 conversions = 705536 threads
  prep_kernel<<<2757, 256, 0, stream>>>(W1, W2, known, kf, w1b, w2b, stats, kprep, X);
  nn_kernel<<<dim3(128, 8), 512, 0, stream>>>(unknown, kprep, widx, wwgt);
  // gemm1: fused interp from bf16 kf (X region); batch->XCD swizzle; 8 waves/block
  gemm1_fused<<<1024, 512, 0, stream>>>(X, uf, widx, wwgt, w1b, b1, Y1, sum1, sq1);
  // gemm2: BN1 finalized in-kernel; fused BN1+ReLU on A; y2 -> X (overwrites kfb)
  gemm2_kernel<<<1024, 256, 0, stream>>>(Y1, w2b, b2, X, sum2, sq2, sum1, sq1, g1, be1);
  // final: BN2 finalized in-kernel; bf16 y2 -> fp32 d_out
  final_kernel<<<8192, 256, 0, stream>>>(X, out, sum2, sq2, g2, be2);
}

// Round 19
// 151.824 us; speedup vs baseline: 1.0326x; 1.0009x over previous
//
#include <hip/hip_runtime.h>

// ---------- problem constants ----------
#define BQ   8
#define NQ   8192      // unknown points per batch
#define MK   2048      // known points per batch
#define C1v  128
#define C2v  256
#define CIN  384
#define HH   256
#define MTOT (BQ*NQ)   // 65536

#define NCHUNK 8       // candidate chunks per nn block (= waves per block)
#define CHSZ   (MK/NCHUNK)   // 256 candidates per chunk

typedef __attribute__((ext_vector_type(8))) __bf16 bf16x8;
typedef __attribute__((ext_vector_type(4))) float f32x4;
typedef __attribute__((ext_vector_type(8))) unsigned short us8;
typedef __attribute__((ext_vector_type(4))) unsigned short us4;
typedef __attribute__((ext_vector_type(2))) unsigned short us2;

__device__ __forceinline__ unsigned short f2bf(float f) {
  unsigned int u = __builtin_bit_cast(unsigned int, f);
  u += 0x7fffu + ((u >> 16) & 1u);           // round-to-nearest-even
  return (unsigned short)(u >> 16);
}
__device__ __forceinline__ float bf2f(unsigned short h) {
  unsigned int u = ((unsigned int)h) << 16;
  return __builtin_bit_cast(float, u);
}

__device__ __forceinline__ void gload16(const void* g, void* l) {
  __builtin_amdgcn_global_load_lds((const __attribute__((address_space(1))) void*)g,
                                   (__attribute__((address_space(3))) void*)l, 16, 0, 0);
}

// packed f32->bf16 RNE convert (dst.lo = src0, dst.hi = src1)
__device__ __forceinline__ unsigned int cvtpk_bf16(float lo, float hi) {
  unsigned int r;
  asm("v_cvt_pk_bf16_f32 %0, %1, %2" : "=v"(r) : "v"(lo), "v"(hi));
  return r;
}

// score from a staged candidate: s = u.k - 0.5|k|^2  (kprep.w = -0.5|k|^2)
#define SCORE(k4) (fmaf((k4).x, ux, fmaf((k4).y, uy, (k4).z * uz)) + (k4).w)

// pack fp32 score + candidate index into one exactly-ordered f64 key:
// (double)s has 29 zero low mantissa bits; OR in (2047-j). Distinct fp32
// scores keep exact order; equal scores tie-break to smaller j (top_k rule).
__device__ __forceinline__ double packsd(float s, int negj) {
  unsigned long long u = __builtin_bit_cast(unsigned long long, (double)s)
                       | (unsigned long long)(unsigned int)negj;
  return __builtin_bit_cast(double, u);
}

// 5-op f64 top-3 insert (keys are all distinct): {s0,s1,s2} <- top3 of {s0,s1,s2,t}
#define INS3D(s0, s1, s2, t)                                  \
  do {                                                        \
    double _hi0 = fmax(s0, (t)), _lo0 = fmin(s0, (t));        \
    double _hi1 = fmax(s1, _lo0), _lo1 = fmin(s1, _lo0);      \
    s0 = _hi0; s1 = _hi1; s2 = fmax(s2, _lo1);                \
  } while (0)

// ---------- 1. prep: W->bf16, BN accum zero, kprep, kf->bf16 (kfb) ----------
__global__ __launch_bounds__(256)
void prep_kernel(const float* __restrict__ W1, const float* __restrict__ W2,
                 const float* __restrict__ known, const float* __restrict__ kf,
                 unsigned short* __restrict__ w1b, unsigned short* __restrict__ w2b,
                 float* __restrict__ stats, float4* __restrict__ kprep,
                 unsigned short* __restrict__ kfb) {
  int i = blockIdx.x * 256 + threadIdx.x;
  if (i < HH*CIN) w1b[i] = f2bf(W1[i]);
  else if (i < HH*CIN + HH*HH) w2b[i - HH*CIN] = f2bf(W2[i - HH*CIN]);
  int z = i - (HH*CIN + HH*HH);
  if (z >= 0 && z < 1024) stats[z] = 0.f;
  int z2 = i - (HH*CIN + HH*HH + 1024);
  if (z2 >= 0 && z2 < BQ*MK) {
    const float* kp = known + (size_t)z2 * 3;
    float x = kp[0], y = kp[1], zz = kp[2];
    kprep[z2] = make_float4(x, y, zz, -0.5f*(x*x + y*y + zz*zz));
  }
  int z3 = i - (HH*CIN + HH*HH + 1024 + BQ*MK);
  if (z3 >= 0 && z3 < (BQ*MK*C2v)/8) {
    const float4* src = (const float4*)(kf + (size_t)z3 * 8);
    float4 v0 = src[0], v1 = src[1];
    us8 o;
    o[0]=f2bf(v0.x); o[1]=f2bf(v0.y); o[2]=f2bf(v0.z); o[3]=f2bf(v0.w);
    o[4]=f2bf(v1.x); o[5]=f2bf(v1.y); o[6]=f2bf(v1.z); o[7]=f2bf(v1.w);
    *(us8*)(kfb + (size_t)z3 * 8) = o;
  }
}

// ---------- 2. three_nn: single pass, index-packed f64 keys (round-14 proven) ----------
__global__ __launch_bounds__(512)
void nn_kernel(const float* __restrict__ unknown, const float4* __restrict__ kprep,
               int* __restrict__ widx, float* __restrict__ wwgt) {
  __shared__ double pd[NCHUNK][64][3];      // per-chunk packed triples (12 KB)
  const int b = blockIdx.y;
  const int tid = threadIdx.x;
  const int wave = tid >> 6, lane = tid & 63;

  const int q = blockIdx.x * 64 + lane;
  const float* up = unknown + ((size_t)b * NQ + q) * 3;
  const float ux = up[0], uy = up[1], uz = up[2];
  const float nu = ux*ux + uy*uy + uz*uz;
  const int jbase = wave * CHSZ;
  // wave-uniform chunk pointer -> scalar-path candidate fetch
  const float4* cp = kprep + (b << 11) + __builtin_amdgcn_readfirstlane(jbase);

  // dual accumulator sets for ILP; keys are distinct so merge order is free
  double A0=-1e300, A1=-1e300, A2=-1e300;
  double B0=-1e300, B1=-1e300, B2=-1e300;
  #pragma unroll 4
  for (int j = 0; j < CHSZ; j += 2) {
    float4 ka = cp[j];
    float4 kc = cp[j+1];
    float sA = SCORE(ka);
    float sB = SCORE(kc);
    double da = packsd(sA, 2047 - (jbase + j));
    double db = packsd(sB, 2047 - (jbase + j + 1));
    INS3D(A0, A1, A2, da);
    INS3D(B0, B1, B2, db);
  }
  INS3D(A0, A1, A2, B0);
  INS3D(A0, A1, A2, B1);
  INS3D(A0, A1, A2, B2);
  pd[wave][lane][0] = A0; pd[wave][lane][1] = A1; pd[wave][lane][2] = A2;
  __syncthreads();

  if (tid < 64) {   // wave 0: lane == query; merge the 8 chunk triples
    double f0=-1e300, f1=-1e300, f2=-1e300;
    #pragma unroll
    for (int c = 0; c < NCHUNK; ++c) {
      INS3D(f0, f1, f2, pd[c][tid][0]);
      INS3D(f0, f1, f2, pd[c][tid][1]);
      INS3D(f0, f1, f2, pd[c][tid][2]);
    }
    unsigned long long u0 = __builtin_bit_cast(unsigned long long, f0);
    unsigned long long u1 = __builtin_bit_cast(unsigned long long, f1);
    unsigned long long u2 = __builtin_bit_cast(unsigned long long, f2);
    int x0 = 2047 - (int)(u0 & 2047ULL);
    int x1 = 2047 - (int)(u1 & 2047ULL);
    int x2 = 2047 - (int)(u2 & 2047ULL);
    // masking restores the exact fp32 score bits
    float s0 = (float)__builtin_bit_cast(double, u0 & ~2047ULL);
    float s1 = (float)__builtin_bit_cast(double, u1 & ~2047ULL);
    float s2 = (float)__builtin_bit_cast(double, u2 & ~2047ULL);
    float d0 = sqrtf(fmaxf(nu - 2.f*s0, 0.f)) + 1e-10f;
    float d1 = sqrtf(fmaxf(nu - 2.f*s1, 0.f)) + 1e-10f;
    float d2 = sqrtf(fmaxf(nu - 2.f*s2, 0.f)) + 1e-10f;
    float r0 = 1.f/d0, r1 = 1.f/d1, r2 = 1.f/d2;
    float rs = 1.f/(r0 + r1 + r2);
    size_t p = (size_t)b * NQ + q;
    widx[p*3+0] = x0;    widx[p*3+1] = x1;    widx[p*3+2] = x2;
    wwgt[p*3+0] = r0*rs; wwgt[p*3+1] = r1*rs; wwgt[p*3+2] = r2*rs;
  }
}

// ---------- 3. GEMM1 (fused interp), 8 waves/block for gather-latency hiding.
// A built in-staging from bf16-kf gathers (3x16B per chunk, 2 chunks/thread)
// + uf concat. Straight load->lerp->ds_write (no cross-iteration state).
// Block swizzle: batch = wid&7 -> all 128 blocks of a batch land on one XCD.
__global__ __launch_bounds__(512)
void gemm1_fused(const unsigned short* __restrict__ kfb, const float* __restrict__ uf,
                 const int* __restrict__ widx, const float* __restrict__ wwgt,
                 const unsigned short* __restrict__ Bw,
                 const float* __restrict__ bias,
                 unsigned short* __restrict__ Out,
                 float* __restrict__ gsum, float* __restrict__ gsq) {
  constexpr int K = CIN;
  __shared__ unsigned short As[128][64];   // 16 KB
  __shared__ unsigned short Bs[128][64];   // 16 KB
  const int tid  = threadIdx.x;
  const int lane = tid & 63;
  const int wave = tid >> 6;          // 0..7
  const int wid   = blockIdx.x;
  const int batch = wid & 7;          // -> XCD id
  const int inner = wid >> 3;         // 0..127 within batch
  const int bm = batch * 64 + (inner >> 1);
  const int bn = inner & 1;
  const int wm = wave >> 1;           // 0..3: 32-row slice
  const int wn = wave & 1;            // 0..1: 64-col slice

  // prologue: per-chunk gather byte-offsets + weights (chunk i -> fixed row/col)
  unsigned int voK0[2], voK1[2], voK2[2], voU[2];
  float w0r[2], w1r[2], w2r[2];
  #pragma unroll
  for (int i = 0; i < 2; ++i) {
    const int c = i*512 + tid;
    const int row = c >> 3;
    const int colK = (c & 7) * 16;     // byte offset within 512 B bf16 row
    const int colU = (c & 7) * 32;     // byte offset within 512 B fp32 row
    const int p = bm*128 + row;
    const int b = p >> 13;
    w0r[i] = wwgt[p*3+0]; w1r[i] = wwgt[p*3+1]; w2r[i] = wwgt[p*3+2];
    voK0[i] = ((unsigned)((b << 11) + widx[p*3+0]) << 9) + colK;
    voK1[i] = ((unsigned)((b << 11) + widx[p*3+1]) << 9) + colK;
    voK2[i] = ((unsigned)((b << 11) + widx[p*3+2]) << 9) + colK;
    voU[i]  = (unsigned)p * 512u + colU;
  }

  f32x4 acc[2][4];
  const f32x4 zero = {0.f, 0.f, 0.f, 0.f};
  #pragma unroll
  for (int m = 0; m < 2; ++m)
    #pragma unroll
    for (int n = 0; n < 4; ++n) acc[m][n] = zero;

  const char* kfbb = (const char*)kfb;
  const char* ufb  = (const char*)uf;

  #pragma unroll
  for (int t = 0; t < 6; ++t) {
    const int k0 = t * 64;
    // B-tile: async LDS-direct (2 chunks per thread via wave-uniform bases)
    #pragma unroll
    for (int i = 0; i < 2; ++i) {
      const int cbase = i*512 + wave*64;
      const int c = cbase + lane;
      const int brow = c >> 3, bcol = (c & 7) * 8;
      gload16(Bw + ((size_t)(bn*128 + brow))*K + k0 + bcol, (unsigned short*)Bs + cbase*8);
    }
    // A-tile: load all gathers for this iteration, then lerp/convert/write
    if (t < 4) {
      us8 GA[2], GE[2], GG[2];
      #pragma unroll
      for (int i = 0; i < 2; ++i) {
        GA[i] = *(const us8*)(kfbb + voK0[i] + t*128);
        GE[i] = *(const us8*)(kfbb + voK1[i] + t*128);
        GG[i] = *(const us8*)(kfbb + voK2[i] + t*128);
      }
      #pragma unroll
      for (int i = 0; i < 2; ++i) {
        const int c = i*512 + tid;
        const float w0 = w0r[i], w1 = w1r[i], w2 = w2r[i];
        float r[8];
        #pragma unroll
        for (int j = 0; j < 8; ++j) {
          float fa = bf2f((unsigned short)GA[i][j]);
          float fe = bf2f((unsigned short)GE[i][j]);
          float fg = bf2f((unsigned short)GG[i][j]);
          r[j] = w0*fa + w1*fe + w2*fg;
        }
        uint4 ov;
        ov.x = cvtpk_bf16(r[0], r[1]);
        ov.y = cvtpk_bf16(r[2], r[3]);
        ov.z = cvtpk_bf16(r[4], r[5]);
        ov.w = cvtpk_bf16(r[6], r[7]);
        *(uint4*)((unsigned short*)As + (size_t)c*8) = ov;
      }
    } else {
      float4 U0[2], U1[2];
      #pragma unroll
      for (int i = 0; i < 2; ++i) {
        U0[i] = *(const float4*)(ufb + voU[i] + (t-4)*256);
        U1[i] = *(const float4*)(ufb + voU[i] + (t-4)*256 + 16);
      }
      #pragma unroll
      for (int i = 0; i < 2; ++i) {
        const int c = i*512 + tid;
        uint4 ov;
        ov.x = cvtpk_bf16(U0[i].x, U0[i].y);
        ov.y = cvtpk_bf16(U0[i].z, U0[i].w);
        ov.z = cvtpk_bf16(U1[i].x, U1[i].y);
        ov.w = cvtpk_bf16(U1[i].z, U1[i].w);
        *(uint4*)((unsigned short*)As + (size_t)c*8) = ov;
      }
    }
    __syncthreads();
    const int kq = (lane >> 4) * 8;
    #pragma unroll
    for (int kk = 0; kk < 64; kk += 32) {
      bf16x8 af[2], bfr[4];
      #pragma unroll
      for (int m = 0; m < 2; ++m)
        af[m] = *(const bf16x8*)&As[wm*32 + m*16 + (lane & 15)][kk + kq];
      #pragma unroll
      for (int n = 0; n < 4; ++n)
        bfr[n] = *(const bf16x8*)&Bs[wn*64 + n*16 + (lane & 15)][kk + kq];
      #pragma unroll
      for (int m = 0; m < 2; ++m)
        #pragma unroll
        for (int n = 0; n < 4; ++n)
          acc[m][n] = __builtin_amdgcn_mfma_f32_16x16x32_bf16(af[m], bfr[n], acc[m][n], 0, 0, 0);
    }
    __syncthreads();
  }

  // epilogue: bias, store bf16, per-channel sum/sumsq (per-wm partials)
  float* s_sum = (float*)&As[0][0];   // [4][128]
  float* s_sq  = s_sum + 512;         // [4][128]
  #pragma unroll
  for (int n = 0; n < 4; ++n) {
    const int cb   = wn*64 + n*16 + (lane & 15);
    const int gcol = bn*128 + cb;
    const float bv = bias[gcol];
    float sum = 0.f, sq = 0.f;
    #pragma unroll
    for (int m = 0; m < 2; ++m) {
      const size_t grow = (size_t)bm*128 + wm*32 + m*16 + (lane >> 4)*4;
      #pragma unroll
      for (int qq = 0; qq < 4; ++qq) {
        float y = acc[m][n][qq] + bv;
        sum += y; sq += y*y;
        Out[(grow+qq)*256 + gcol] = f2bf(y);
      }
    }
    sum += __shfl_xor(sum, 16, 64); sum += __shfl_xor(sum, 32, 64);
    sq  += __shfl_xor(sq , 16, 64); sq  += __shfl_xor(sq , 32, 64);
    if (lane < 16) { s_sum[wm*128 + cb] = sum; s_sq[wm*128 + cb] = sq; }
  }
  __syncthreads();
  if (tid < 128) {
    float ts = s_sum[tid] + s_sum[128+tid] + s_sum[256+tid] + s_sum[384+tid];
    float tq = s_sq [tid] + s_sq [128+tid] + s_sq [256+tid] + s_sq [384+tid];
    atomicAdd(&gsum[bn*128 + tid], ts);
    atomicAdd(&gsq [bn*128 + tid], tq);
  }
}

// ---------- 4. GEMM2: fused BN1+ReLU on A-load (scale/shift computed in preamble
// from raw sums), y2 bf16 out, + BN2 stats ----------
__global__ __launch_bounds__(256)
void gemm2_kernel(const unsigned short* __restrict__ A,     // y1 raw bf16
                  const unsigned short* __restrict__ Bw,    // W2 bf16
                  const float* __restrict__ bias,           // b2
                  unsigned short* __restrict__ Out,         // y2 bf16
                  float* __restrict__ gsum, float* __restrict__ gsq,     // BN2 accum
                  const float* __restrict__ gsum1, const float* __restrict__ gsq1,
                  const float* __restrict__ g1, const float* __restrict__ be1) {
  constexpr int K = HH;
  __shared__ unsigned short As[128][64];   // 16 KB
  __shared__ unsigned short Bs[128][64];   // 16 KB
  __shared__ float sc_l[HH], sh_l[HH];     // 2 KB
  const int tid  = threadIdx.x;
  const int lane = tid & 63;
  const int wave = tid >> 6;          // 0..3
  const int wid  = blockIdx.x;
  const int slot = wid & 15;
  const int bm = ((wid >> 4) << 3) | (slot & 7);
  const int bn = slot >> 3;
  const int wm = wave >> 1, wn = wave & 1;

  {  // BN1 finalize (redundant per block; replaces stats_fin dispatch)
    float mu  = gsum1[tid] * (1.f/65536.f);
    float var = gsq1[tid]  * (1.f/65536.f) - mu*mu;
    float sc  = g1[tid] * rsqrtf(var + 1e-5f);
    sc_l[tid] = sc;
    sh_l[tid] = be1[tid] - mu*sc;
  }
  __syncthreads();

  f32x4 acc[4][4];
  const f32x4 zero = {0.f, 0.f, 0.f, 0.f};
  #pragma unroll
  for (int m = 0; m < 4; ++m)
    #pragma unroll
    for (int n = 0; n < 4; ++n) acc[m][n] = zero;

  for (int k0 = 0; k0 < K; k0 += 64) {
    #pragma unroll
    for (int i = 0; i < 4; ++i) {
      const int cbase = wave*64 + i*256;          // wave-uniform chunk base
      const int c = cbase + lane;                 // per-lane chunk (16 B)
      const int row = c >> 3, col = (c & 7) * 8;
      gload16(Bw + ((size_t)(bn*128 + row))*K + k0 + col, (unsigned short*)Bs + cbase*8);
      us8 v = *(const us8*)(A + ((size_t)(bm*128 + row))*K + k0 + col);
      us8 o;
      #pragma unroll
      for (int j = 0; j < 8; ++j) {
        float y = fmaxf(fmaf(bf2f(v[j]), sc_l[k0+col+j], sh_l[k0+col+j]), 0.f);
        o[j] = f2bf(y);
      }
      *(us8*)((unsigned short*)As + cbase*8 + lane*8) = o;
    }
    __syncthreads();
    const int kq = (lane >> 4) * 8;
    #pragma unroll
    for (int kk = 0; kk < 64; kk += 32) {
      bf16x8 af[4], bfr[4];
      #pragma unroll
      for (int m = 0; m < 4; ++m)
        af[m] = *(const bf16x8*)&As[wm*64 + m*16 + (lane & 15)][kk + kq];
      #pragma unroll
      for (int n = 0; n < 4; ++n)
        bfr[n] = *(const bf16x8*)&Bs[wn*64 + n*16 + (lane & 15)][kk + kq];
      #pragma unroll
      for (int m = 0; m < 4; ++m)
        #pragma unroll
        for (int n = 0; n < 4; ++n)
          acc[m][n] = __builtin_amdgcn_mfma_f32_16x16x32_bf16(af[m], bfr[n], acc[m][n], 0, 0, 0);
    }
    __syncthreads();
  }

  // epilogue: bias, store bf16 y2, per-channel sum/sumsq
  float* s_sum = (float*)&As[0][0];   // [2][128]
  float* s_sq  = s_sum + 256;         // [2][128]
  #pragma unroll
  for (int n = 0; n < 4; ++n) {
    const int cb   = wn*64 + n*16 + (lane & 15);
    const int gcol = bn*128 + cb;
    const float bv = bias[gcol];
    float sum = 0.f, sq = 0.f;
    #pragma unroll
    for (int m = 0; m < 4; ++m) {
      const size_t grow = (size_t)bm*128 + wm*64 + m*16 + (lane >> 4)*4;
      #pragma unroll
      for (int qq = 0; qq < 4; ++qq) {
        float y = acc[m][n][qq] + bv;
        sum += y; sq += y*y;
        Out[(grow+qq)*256 + gcol] = f2bf(y);
      }
    }
    sum += __shfl_xor(sum, 16, 64); sum += __shfl_xor(sum, 32, 64);
    sq  += __shfl_xor(sq , 16, 64); sq  += __shfl_xor(sq , 32, 64);
    if (lane < 16) { s_sum[wm*128 + cb] = sum; s_sq[wm*128 + cb] = sq; }
  }
  __syncthreads();
  if (tid < 128) {
    atomicAdd(&gsum[bn*128 + tid], s_sum[tid] + s_sum[128 + tid]);
    atomicAdd(&gsq [bn*128 + tid], s_sq [tid] + s_sq [128 + tid]);
  }
}

// ---------- 5. final BN2+ReLU: bf16 y2 -> fp32 d_out (scale/shift in preamble) ----------
__global__ __launch_bounds__(256)
void final_kernel(const unsigned short* __restrict__ Y2, float* __restrict__ Out,
                  const float* __restrict__ gsum, const float* __restrict__ gsq,
                  const float* __restrict__ g2, const float* __restrict__ be2) {
  __shared__ float sc[256], sh[256];
  {  // BN2 finalize (redundant per block; replaces stats_fin dispatch)
    float mu  = gsum[threadIdx.x] * (1.f/65536.f);
    float var = gsq[threadIdx.x]  * (1.f/65536.f) - mu*mu;
    float scv = g2[threadIdx.x] * rsqrtf(var + 1e-5f);
    sc[threadIdx.x] = scv;
    sh[threadIdx.x] = be2[threadIdx.x] - mu*scv;
  }
  __syncthreads();
  size_t i = ((size_t)blockIdx.x * 256 + threadIdx.x) * 8;
  int c0 = (int)(i & 255);
  us8 v = *(const us8*)(Y2 + i);
  float4 o1, o2;
  o1.x = fmaxf(fmaf(bf2f(v[0]), sc[c0+0], sh[c0+0]), 0.f);
  o1.y = fmaxf(fmaf(bf2f(v[1]), sc[c0+1], sh[c0+1]), 0.f);
  o1.z = fmaxf(fmaf(bf2f(v[2]), sc[c0+2], sh[c0+2]), 0.f);
  o1.w = fmaxf(fmaf(bf2f(v[3]), sc[c0+3], sh[c0+3]), 0.f);
  o2.x = fmaxf(fmaf(bf2f(v[4]), sc[c0+4], sh[c0+4]), 0.f);
  o2.y = fmaxf(fmaf(bf2f(v[5]), sc[c0+5], sh[c0+5]), 0.f);
  o2.z = fmaxf(fmaf(bf2f(v[6]), sc[c0+6], sh[c0+6]), 0.f);
  o2.w = fmaxf(fmaf(bf2f(v[7]), sc[c0+7], sh[c0+7]), 0.f);
  *(float4*)(Out + i)     = o1;
  *(float4*)(Out + i + 4) = o2;
}

// ---------- launch ----------
extern "C" void kernel_launch(void* const* d_in, const int* in_sizes, int n_in,
                              void* d_out, int out_size, void* d_ws, size_t ws_size,
                              hipStream_t stream) {
  const float* unknown = (const float*)d_in[0];
  const float* known   = (const float*)d_in[1];
  const float* uf      = (const float*)d_in[2];
  const float* kf      = (const float*)d_in[3];
  const float* W1      = (const float*)d_in[4];
  const float* b1      = (const float*)d_in[5];
  const float* g1      = (const float*)d_in[6];
  const float* be1     = (const float*)d_in[7];
  const float* W2      = (const float*)d_in[8];
  const float* b2      = (const float*)d_in[9];
  const float* g2      = (const float*)d_in[10];
  const float* be2     = (const float*)d_in[11];

  char* ws = (char*)d_ws;
  unsigned short* X    = (unsigned short*)(ws);                 // kfb (8.4 MB) during gemm1, then y2 (33.5 MB)
  unsigned short* Y1   = (unsigned short*)(ws + 50331648);      // 33,554,432 (y1 raw)
  unsigned short* w1b  = (unsigned short*)(ws + 83886080);      // 196,608
  unsigned short* w2b  = (unsigned short*)(ws + 84082688);      // 131,072
  int*            widx = (int*)  (ws + 84213760);               // 786,432
  float*          wwgt = (float*)(ws + 85000192);               // 786,432
  float*          stats= (float*)(ws + 85786624);               // 8 KB
  float4*         kprep= (float4*)(ws + 85794816);              // 262,144
  float *sum1 = stats,        *sq1 = stats + 256;
  float *sum2 = stats + 512,  *sq2 = stats + 768;
  float* out = (float*)d_out;

  // prep: 181248 small items + 524288 kf->bf16 conversions = 705536 threads
  prep_kernel<<<2757, 256, 0, stream>>>(W1, W2, known, kf, w1b, w2b, stats, kprep, X);
  nn_kernel<<<dim3(128, 8), 512, 0, stream>>>(unknown, kprep, widx, wwgt);
  // gemm1: fused interp from bf16 kf (X region); batch->XCD swizzle; 8 waves/block
  gemm1_fused<<<1024, 512, 0, stream>>>(X, uf, widx, wwgt, w1b, b1, Y1, sum1, sq1);
  // gemm2: BN1 finalized in-kernel; fused BN1+ReLU on A; y2 -> X (overwrites kfb)
  gemm2_kernel<<<1024, 256, 0, stream>>>(Y1, w2b, b2, X, sum2, sq2, sum1, sq1, g1, be1);
  // final: BN2 finalized in-kernel; bf16 y2 -> fp32 d_out
  final_kernel<<<8192, 256, 0, stream>>>(X, out, sum2, sq2, g2, be2);
}

// Round 20
// 150.240 us; speedup vs baseline: 1.0435x; 1.0105x over previous
//
#include <hip/hip_runtime.h>

// ---------- problem constants ----------
#define BQ   8
#define NQ   8192      // unknown points per batch
#define MK   2048      // known points per batch
#define C1v  128
#define C2v  256
#define CIN  384
#define HH   256
#define MTOT (BQ*NQ)   // 65536

#define NCHUNK 8       // candidate chunks per nn block (= waves per block)
#define CHSZ   (MK/NCHUNK)   // 256 candidates per chunk

typedef __attribute__((ext_vector_type(8))) __bf16 bf16x8;
typedef __attribute__((ext_vector_type(4))) float f32x4;
typedef __attribute__((ext_vector_type(8))) unsigned short us8;
typedef __attribute__((ext_vector_type(4))) unsigned short us4;
typedef __attribute__((ext_vector_type(2))) unsigned short us2;

__device__ __forceinline__ unsigned short f2bf(float f) {
  unsigned int u = __builtin_bit_cast(unsigned int, f);
  u += 0x7fffu + ((u >> 16) & 1u);           // round-to-nearest-even
  return (unsigned short)(u >> 16);
}
__device__ __forceinline__ float bf2f(unsigned short h) {
  unsigned int u = ((unsigned int)h) << 16;
  return __builtin_bit_cast(float, u);
}

__device__ __forceinline__ void gload16(const void* g, void* l) {
  __builtin_amdgcn_global_load_lds((const __attribute__((address_space(1))) void*)g,
                                   (__attribute__((address_space(3))) void*)l, 16, 0, 0);
}

// packed f32->bf16 RNE convert (dst.lo = src0, dst.hi = src1)
__device__ __forceinline__ unsigned int cvtpk_bf16(float lo, float hi) {
  unsigned int r;
  asm("v_cvt_pk_bf16_f32 %0, %1, %2" : "=v"(r) : "v"(lo), "v"(hi));
  return r;
}

// score from a staged candidate: s = u.k - 0.5|k|^2  (kprep.w = -0.5|k|^2)
#define SCORE(k4) (fmaf((k4).x, ux, fmaf((k4).y, uy, (k4).z * uz)) + (k4).w)

// pack fp32 score + candidate index into one exactly-ordered f64 key:
// (double)s has 29 zero low mantissa bits; OR in (2047-j). Distinct fp32
// scores keep exact order; equal scores tie-break to smaller j (top_k rule).
__device__ __forceinline__ double packsd(float s, int negj) {
  unsigned long long u = __builtin_bit_cast(unsigned long long, (double)s)
                       | (unsigned long long)(unsigned int)negj;
  return __builtin_bit_cast(double, u);
}

// 5-op f64 top-3 insert (keys are all distinct): {s0,s1,s2} <- top3 of {s0,s1,s2,t}
#define INS3D(s0, s1, s2, t)                                  \
  do {                                                        \
    double _hi0 = fmax(s0, (t)), _lo0 = fmin(s0, (t));        \
    double _hi1 = fmax(s1, _lo0), _lo1 = fmin(s1, _lo0);      \
    s0 = _hi0; s1 = _hi1; s2 = fmax(s2, _lo1);                \
  } while (0)

// ---------- 1. prep: W->bf16, BN accum zero, kprep, kf->bf16 (kfb) ----------
__global__ __launch_bounds__(256)
void prep_kernel(const float* __restrict__ W1, const float* __restrict__ W2,
                 const float* __restrict__ known, const float* __restrict__ kf,
                 unsigned short* __restrict__ w1b, unsigned short* __restrict__ w2b,
                 float* __restrict__ stats, float4* __restrict__ kprep,
                 unsigned short* __restrict__ kfb) {
  int i = blockIdx.x * 256 + threadIdx.x;
  if (i < HH*CIN) w1b[i] = f2bf(W1[i]);
  else if (i < HH*CIN + HH*HH) w2b[i - HH*CIN] = f2bf(W2[i - HH*CIN]);
  int z = i - (HH*CIN + HH*HH);
  if (z >= 0 && z < 1024) stats[z] = 0.f;
  int z2 = i - (HH*CIN + HH*HH + 1024);
  if (z2 >= 0 && z2 < BQ*MK) {
    const float* kp = known + (size_t)z2 * 3;
    float x = kp[0], y = kp[1], zz = kp[2];
    kprep[z2] = make_float4(x, y, zz, -0.5f*(x*x + y*y + zz*zz));
  }
  int z3 = i - (HH*CIN + HH*HH + 1024 + BQ*MK);
  if (z3 >= 0 && z3 < (BQ*MK*C2v)/8) {
    const float4* src = (const float4*)(kf + (size_t)z3 * 8);
    float4 v0 = src[0], v1 = src[1];
    us8 o;
    o[0]=f2bf(v0.x); o[1]=f2bf(v0.y); o[2]=f2bf(v0.z); o[3]=f2bf(v0.w);
    o[4]=f2bf(v1.x); o[5]=f2bf(v1.y); o[6]=f2bf(v1.z); o[7]=f2bf(v1.w);
    *(us8*)(kfb + (size_t)z3 * 8) = o;
  }
}

// ---------- 2. three_nn: single pass, index-packed f64 keys (round-14 proven) ----------
__global__ __launch_bounds__(512)
void nn_kernel(const float* __restrict__ unknown, const float4* __restrict__ kprep,
               int* __restrict__ widx, float* __restrict__ wwgt) {
  __shared__ double pd[NCHUNK][64][3];      // per-chunk packed triples (12 KB)
  const int b = blockIdx.y;
  const int tid = threadIdx.x;
  const int wave = tid >> 6, lane = tid & 63;

  const int q = blockIdx.x * 64 + lane;
  const float* up = unknown + ((size_t)b * NQ + q) * 3;
  const float ux = up[0], uy = up[1], uz = up[2];
  const float nu = ux*ux + uy*uy + uz*uz;
  const int jbase = wave * CHSZ;
  // wave-uniform chunk pointer -> scalar-path candidate fetch
  const float4* cp = kprep + (b << 11) + __builtin_amdgcn_readfirstlane(jbase);

  // dual accumulator sets for ILP; keys are distinct so merge order is free
  double A0=-1e300, A1=-1e300, A2=-1e300;
  double B0=-1e300, B1=-1e300, B2=-1e300;
  #pragma unroll 4
  for (int j = 0; j < CHSZ; j += 2) {
    float4 ka = cp[j];
    float4 kc = cp[j+1];
    float sA = SCORE(ka);
    float sB = SCORE(kc);
    double da = packsd(sA, 2047 - (jbase + j));
    double db = packsd(sB, 2047 - (jbase + j + 1));
    INS3D(A0, A1, A2, da);
    INS3D(B0, B1, B2, db);
  }
  INS3D(A0, A1, A2, B0);
  INS3D(A0, A1, A2, B1);
  INS3D(A0, A1, A2, B2);
  pd[wave][lane][0] = A0; pd[wave][lane][1] = A1; pd[wave][lane][2] = A2;
  __syncthreads();

  if (tid < 64) {   // wave 0: lane == query; merge the 8 chunk triples
    double f0=-1e300, f1=-1e300, f2=-1e300;
    #pragma unroll
    for (int c = 0; c < NCHUNK; ++c) {
      INS3D(f0, f1, f2, pd[c][tid][0]);
      INS3D(f0, f1, f2, pd[c][tid][1]);
      INS3D(f0, f1, f2, pd[c][tid][2]);
    }
    unsigned long long u0 = __builtin_bit_cast(unsigned long long, f0);
    unsigned long long u1 = __builtin_bit_cast(unsigned long long, f1);
    unsigned long long u2 = __builtin_bit_cast(unsigned long long, f2);
    int x0 = 2047 - (int)(u0 & 2047ULL);
    int x1 = 2047 - (int)(u1 & 2047ULL);
    int x2 = 2047 - (int)(u2 & 2047ULL);
    // masking restores the exact fp32 score bits
    float s0 = (float)__builtin_bit_cast(double, u0 & ~2047ULL);
    float s1 = (float)__builtin_bit_cast(double, u1 & ~2047ULL);
    float s2 = (float)__builtin_bit_cast(double, u2 & ~2047ULL);
    float d0 = sqrtf(fmaxf(nu - 2.f*s0, 0.f)) + 1e-10f;
    float d1 = sqrtf(fmaxf(nu - 2.f*s1, 0.f)) + 1e-10f;
    float d2 = sqrtf(fmaxf(nu - 2.f*s2, 0.f)) + 1e-10f;
    float r0 = 1.f/d0, r1 = 1.f/d1, r2 = 1.f/d2;
    float rs = 1.f/(r0 + r1 + r2);
    size_t p = (size_t)b * NQ + q;
    widx[p*3+0] = x0;    widx[p*3+1] = x1;    widx[p*3+2] = x2;
    wwgt[p*3+0] = r0*rs; wwgt[p*3+1] = r1*rs; wwgt[p*3+2] = r2*rs;
  }
}

// ---------- 3. GEMM1 (fused interp), 8 waves/block for gather-latency hiding.
// A built in-staging from bf16-kf gathers (3x16B per chunk, 2 chunks/thread)
// + uf concat. Straight load->lerp->ds_write (no cross-iteration state).
// Block swizzle: batch = wid&7 -> all 128 blocks of a batch land on one XCD.
__global__ __launch_bounds__(512)
void gemm1_fused(const unsigned short* __restrict__ kfb, const float* __restrict__ uf,
                 const int* __restrict__ widx, const float* __restrict__ wwgt,
                 const unsigned short* __restrict__ Bw,
                 const float* __restrict__ bias,
                 unsigned short* __restrict__ Out,
                 float* __restrict__ gsum, float* __restrict__ gsq) {
  constexpr int K = CIN;
  __shared__ unsigned short As[128][64];   // 16 KB
  __shared__ unsigned short Bs[128][64];   // 16 KB
  const int tid  = threadIdx.x;
  const int lane = tid & 63;
  const int wave = tid >> 6;          // 0..7
  const int wid   = blockIdx.x;
  const int batch = wid & 7;          // -> XCD id
  const int inner = wid >> 3;         // 0..127 within batch
  const int bm = batch * 64 + (inner >> 1);
  const int bn = inner & 1;
  const int wm = wave >> 1;           // 0..3: 32-row slice
  const int wn = wave & 1;            // 0..1: 64-col slice

  // prologue: per-chunk gather byte-offsets + weights (chunk i -> fixed row/col)
  unsigned int voK0[2], voK1[2], voK2[2], voU[2];
  float w0r[2], w1r[2], w2r[2];
  #pragma unroll
  for (int i = 0; i < 2; ++i) {
    const int c = i*512 + tid;
    const int row = c >> 3;
    const int colK = (c & 7) * 16;     // byte offset within 512 B bf16 row
    const int colU = (c & 7) * 32;     // byte offset within 512 B fp32 row
    const int p = bm*128 + row;
    const int b = p >> 13;
    w0r[i] = wwgt[p*3+0]; w1r[i] = wwgt[p*3+1]; w2r[i] = wwgt[p*3+2];
    voK0[i] = ((unsigned)((b << 11) + widx[p*3+0]) << 9) + colK;
    voK1[i] = ((unsigned)((b << 11) + widx[p*3+1]) << 9) + colK;
    voK2[i] = ((unsigned)((b << 11) + widx[p*3+2]) << 9) + colK;
    voU[i]  = (unsigned)p * 512u + colU;
  }

  f32x4 acc[2][4];
  const f32x4 zero = {0.f, 0.f, 0.f, 0.f};
  #pragma unroll
  for (int m = 0; m < 2; ++m)
    #pragma unroll
    for (int n = 0; n < 4; ++n) acc[m][n] = zero;

  const char* kfbb = (const char*)kfb;
  const char* ufb  = (const char*)uf;

  #pragma unroll
  for (int t = 0; t < 6; ++t) {
    const int k0 = t * 64;
    // B-tile: async LDS-direct (2 chunks per thread via wave-uniform bases)
    #pragma unroll
    for (int i = 0; i < 2; ++i) {
      const int cbase = i*512 + wave*64;
      const int c = cbase + lane;
      const int brow = c >> 3, bcol = (c & 7) * 8;
      gload16(Bw + ((size_t)(bn*128 + brow))*K + k0 + bcol, (unsigned short*)Bs + cbase*8);
    }
    // A-tile: load all gathers for this iteration, then lerp/convert/write
    if (t < 4) {
      us8 GA[2], GE[2], GG[2];
      #pragma unroll
      for (int i = 0; i < 2; ++i) {
        GA[i] = *(const us8*)(kfbb + voK0[i] + t*128);
        GE[i] = *(const us8*)(kfbb + voK1[i] + t*128);
        GG[i] = *(const us8*)(kfbb + voK2[i] + t*128);
      }
      #pragma unroll
      for (int i = 0; i < 2; ++i) {
        const int c = i*512 + tid;
        const float w0 = w0r[i], w1 = w1r[i], w2 = w2r[i];
        float r[8];
        #pragma unroll
        for (int j = 0; j < 8; ++j) {
          float fa = bf2f((unsigned short)GA[i][j]);
          float fe = bf2f((unsigned short)GE[i][j]);
          float fg = bf2f((unsigned short)GG[i][j]);
          r[j] = w0*fa + w1*fe + w2*fg;
        }
        uint4 ov;
        ov.x = cvtpk_bf16(r[0], r[1]);
        ov.y = cvtpk_bf16(r[2], r[3]);
        ov.z = cvtpk_bf16(r[4], r[5]);
        ov.w = cvtpk_bf16(r[6], r[7]);
        *(uint4*)((unsigned short*)As + (size_t)c*8) = ov;
      }
    } else {
      float4 U0[2], U1[2];
      #pragma unroll
      for (int i = 0; i < 2; ++i) {
        U0[i] = *(const float4*)(ufb + voU[i] + (t-4)*256);
        U1[i] = *(const float4*)(ufb + voU[i] + (t-4)*256 + 16);
      }
      #pragma unroll
      for (int i = 0; i < 2; ++i) {
        const int c = i*512 + tid;
        uint4 ov;
        ov.x = cvtpk_bf16(U0[i].x, U0[i].y);
        ov.y = cvtpk_bf16(U0[i].z, U0[i].w);
        ov.z = cvtpk_bf16(U1[i].x, U1[i].y);
        ov.w = cvtpk_bf16(U1[i].z, U1[i].w);
        *(uint4*)((unsigned short*)As + (size_t)c*8) = ov;
      }
    }
    __syncthreads();
    const int kq = (lane >> 4) * 8;
    #pragma unroll
    for (int kk = 0; kk < 64; kk += 32) {
      bf16x8 af[2], bfr[4];
      #pragma unroll
      for (int m = 0; m < 2; ++m)
        af[m] = *(const bf16x8*)&As[wm*32 + m*16 + (lane & 15)][kk + kq];
      #pragma unroll
      for (int n = 0; n < 4; ++n)
        bfr[n] = *(const bf16x8*)&Bs[wn*64 + n*16 + (lane & 15)][kk + kq];
      #pragma unroll
      for (int m = 0; m < 2; ++m)
        #pragma unroll
        for (int n = 0; n < 4; ++n)
          acc[m][n] = __builtin_amdgcn_mfma_f32_16x16x32_bf16(af[m], bfr[n], acc[m][n], 0, 0, 0);
    }
    __syncthreads();
  }

  // epilogue: bias, store bf16, per-channel sum/sumsq (per-wm partials)
  float* s_sum = (float*)&As[0][0];   // [4][128]
  float* s_sq  = s_sum + 512;         // [4][128]
  #pragma unroll
  for (int n = 0; n < 4; ++n) {
    const int cb   = wn*64 + n*16 + (lane & 15);
    const int gcol = bn*128 + cb;
    const float bv = bias[gcol];
    float sum = 0.f, sq = 0.f;
    #pragma unroll
    for (int m = 0; m < 2; ++m) {
      const size_t grow = (size_t)bm*128 + wm*32 + m*16 + (lane >> 4)*4;
      #pragma unroll
      for (int qq = 0; qq < 4; ++qq) {
        float y = acc[m][n][qq] + bv;
        sum += y; sq += y*y;
        Out[(grow+qq)*256 + gcol] = f2bf(y);
      }
    }
    sum += __shfl_xor(sum, 16, 64); sum += __shfl_xor(sum, 32, 64);
    sq  += __shfl_xor(sq , 16, 64); sq  += __shfl_xor(sq , 32, 64);
    if (lane < 16) { s_sum[wm*128 + cb] = sum; s_sq[wm*128 + cb] = sq; }
  }
  __syncthreads();
  if (tid < 128) {
    float ts = s_sum[tid] + s_sum[128+tid] + s_sum[256+tid] + s_sum[384+tid];
    float tq = s_sq [tid] + s_sq [128+tid] + s_sq [256+tid] + s_sq [384+tid];
    atomicAdd(&gsum[bn*128 + tid], ts);
    atomicAdd(&gsq [bn*128 + tid], tq);
  }
}

// ---------- 4. GEMM2, 8 waves/block (mirrors gemm1's proven structure):
// fused BN1+ReLU on A-load (scale/shift computed in preamble from raw sums),
// y2 bf16 out, + BN2 stats ----------
__global__ __launch_bounds__(512)
void gemm2_kernel(const unsigned short* __restrict__ A,     // y1 raw bf16
                  const unsigned short* __restrict__ Bw,    // W2 bf16
                  const float* __restrict__ bias,           // b2
                  unsigned short* __restrict__ Out,         // y2 bf16
                  float* __restrict__ gsum, float* __restrict__ gsq,     // BN2 accum
                  const float* __restrict__ gsum1, const float* __restrict__ gsq1,
                  const float* __restrict__ g1, const float* __restrict__ be1) {
  constexpr int K = HH;
  __shared__ unsigned short As[128][64];   // 16 KB
  __shared__ unsigned short Bs[128][64];   // 16 KB
  __shared__ float sc_l[HH], sh_l[HH];     // 2 KB
  const int tid  = threadIdx.x;
  const int lane = tid & 63;
  const int wave = tid >> 6;          // 0..7
  const int wid  = blockIdx.x;
  const int slot = wid & 15;
  const int bm = ((wid >> 4) << 3) | (slot & 7);
  const int bn = slot >> 3;
  const int wm = wave >> 1;           // 0..3: 32-row slice
  const int wn = wave & 1;            // 0..1: 64-col slice

  if (tid < HH) {  // BN1 finalize (redundant per block; replaces stats_fin dispatch)
    float mu  = gsum1[tid] * (1.f/65536.f);
    float var = gsq1[tid]  * (1.f/65536.f) - mu*mu;
    float sc  = g1[tid] * rsqrtf(var + 1e-5f);
    sc_l[tid] = sc;
    sh_l[tid] = be1[tid] - mu*sc;
  }
  __syncthreads();

  f32x4 acc[2][4];
  const f32x4 zero = {0.f, 0.f, 0.f, 0.f};
  #pragma unroll
  for (int m = 0; m < 2; ++m)
    #pragma unroll
    for (int n = 0; n < 4; ++n) acc[m][n] = zero;

  #pragma unroll
  for (int t = 0; t < 4; ++t) {
    const int k0 = t * 64;
    // B-tile: async LDS-direct (2 chunks per thread via wave-uniform bases)
    #pragma unroll
    for (int i = 0; i < 2; ++i) {
      const int cbase = i*512 + wave*64;
      const int c = cbase + lane;
      const int brow = c >> 3, bcol = (c & 7) * 8;
      gload16(Bw + ((size_t)(bn*128 + brow))*K + k0 + bcol, (unsigned short*)Bs + cbase*8);
    }
    // A-tile: 2 chunks/thread, BN1+ReLU fused
    us8 V[2];
    #pragma unroll
    for (int i = 0; i < 2; ++i) {
      const int c = i*512 + tid;
      const int row = c >> 3, col = (c & 7) * 8;
      V[i] = *(const us8*)(A + ((size_t)(bm*128 + row))*K + k0 + col);
    }
    #pragma unroll
    for (int i = 0; i < 2; ++i) {
      const int c = i*512 + tid;
      const int col = (c & 7) * 8;
      us8 o;
      #pragma unroll
      for (int j = 0; j < 8; ++j) {
        float y = fmaxf(fmaf(bf2f((unsigned short)V[i][j]), sc_l[k0+col+j], sh_l[k0+col+j]), 0.f);
        o[j] = f2bf(y);
      }
      *(us8*)((unsigned short*)As + (size_t)c*8) = o;
    }
    __syncthreads();
    const int kq = (lane >> 4) * 8;
    #pragma unroll
    for (int kk = 0; kk < 64; kk += 32) {
      bf16x8 af[2], bfr[4];
      #pragma unroll
      for (int m = 0; m < 2; ++m)
        af[m] = *(const bf16x8*)&As[wm*32 + m*16 + (lane & 15)][kk + kq];
      #pragma unroll
      for (int n = 0; n < 4; ++n)
        bfr[n] = *(const bf16x8*)&Bs[wn*64 + n*16 + (lane & 15)][kk + kq];
      #pragma unroll
      for (int m = 0; m < 2; ++m)
        #pragma unroll
        for (int n = 0; n < 4; ++n)
          acc[m][n] = __builtin_amdgcn_mfma_f32_16x16x32_bf16(af[m], bfr[n], acc[m][n], 0, 0, 0);
    }
    __syncthreads();
  }

  // epilogue: bias, store bf16 y2, per-channel sum/sumsq (per-wm partials)
  float* s_sum = (float*)&As[0][0];   // [4][128]
  float* s_sq  = s_sum + 512;         // [4][128]
  #pragma unroll
  for (int n = 0; n < 4; ++n) {
    const int cb   = wn*64 + n*16 + (lane & 15);
    const int gcol = bn*128 + cb;
    const float bv = bias[gcol];
    float sum = 0.f, sq = 0.f;
    #pragma unroll
    for (int m = 0; m < 2; ++m) {
      const size_t grow = (size_t)bm*128 + wm*32 + m*16 + (lane >> 4)*4;
      #pragma unroll
      for (int qq = 0; qq < 4; ++qq) {
        float y = acc[m][n][qq] + bv;
        sum += y; sq += y*y;
        Out[(grow+qq)*256 + gcol] = f2bf(y);
      }
    }
    sum += __shfl_xor(sum, 16, 64); sum += __shfl_xor(sum, 32, 64);
    sq  += __shfl_xor(sq , 16, 64); sq  += __shfl_xor(sq , 32, 64);
    if (lane < 16) { s_sum[wm*128 + cb] = sum; s_sq[wm*128 + cb] = sq; }
  }
  __syncthreads();
  if (tid < 128) {
    float ts = s_sum[tid] + s_sum[128+tid] + s_sum[256+tid] + s_sum[384+tid];
    float tq = s_sq [tid] + s_sq [128+tid] + s_sq [256+tid] + s_sq [384+tid];
    atomicAdd(&gsum[bn*128 + tid], ts);
    atomicAdd(&gsq [bn*128 + tid], tq);
  }
}

// ---------- 5. final BN2+ReLU: bf16 y2 -> fp32 d_out (scale/shift in preamble) ----------
__global__ __launch_bounds__(256)
void final_kernel(const unsigned short* __restrict__ Y2, float* __restrict__ Out,
                  const float* __restrict__ gsum, const float* __restrict__ gsq,
                  const float* __restrict__ g2, const float* __restrict__ be2) {
  __shared__ float sc[256], sh[256];
  {  // BN2 finalize (redundant per block; replaces stats_fin dispatch)
    float mu  = gsum[threadIdx.x] * (1.f/65536.f);
    float var = gsq[threadIdx.x]  * (1.f/65536.f) - mu*mu;
    float scv = g2[threadIdx.x] * rsqrtf(var + 1e-5f);
    sc[threadIdx.x] = scv;
    sh[threadIdx.x] = be2[threadIdx.x] - mu*scv;
  }
  __syncthreads();
  size_t i = ((size_t)blockIdx.x * 256 + threadIdx.x) * 8;
  int c0 = (int)(i & 255);
  us8 v = *(const us8*)(Y2 + i);
  float4 o1, o2;
  o1.x = fmaxf(fmaf(bf2f(v[0]), sc[c0+0], sh[c0+0]), 0.f);
  o1.y = fmaxf(fmaf(bf2f(v[1]), sc[c0+1], sh[c0+1]), 0.f);
  o1.z = fmaxf(fmaf(bf2f(v[2]), sc[c0+2], sh[c0+2]), 0.f);
  o1.w = fmaxf(fmaf(bf2f(v[3]), sc[c0+3], sh[c0+3]), 0.f);
  o2.x = fmaxf(fmaf(bf2f(v[4]), sc[c0+4], sh[c0+4]), 0.f);
  o2.y = fmaxf(fmaf(bf2f(v[5]), sc[c0+5], sh[c0+5]), 0.f);
  o2.z = fmaxf(fmaf(bf2f(v[6]), sc[c0+6], sh[c0+6]), 0.f);
  o2.w = fmaxf(fmaf(bf2f(v[7]), sc[c0+7], sh[c0+7]), 0.f);
  *(float4*)(Out + i)     = o1;
  *(float4*)(Out + i + 4) = o2;
}

// ---------- launch ----------
extern "C" void kernel_launch(void* const* d_in, const int* in_sizes, int n_in,
                              void* d_out, int out_size, void* d_ws, size_t ws_size,
                              hipStream_t stream) {
  const float* unknown = (const float*)d_in[0];
  const float* known   = (const float*)d_in[1];
  const float* uf      = (const float*)d_in[2];
  const float* kf      = (const float*)d_in[3];
  const float* W1      = (const float*)d_in[4];
  const float* b1      = (const float*)d_in[5];
  const float* g1      = (const float*)d_in[6];
  const float* be1     = (const float*)d_in[7];
  const float* W2      = (const float*)d_in[8];
  const float* b2      = (const float*)d_in[9];
  const float* g2      = (const float*)d_in[10];
  const float* be2     = (const float*)d_in[11];

  char* ws = (char*)d_ws;
  unsigned short* X    = (unsigned short*)(ws);                 // kfb (8.4 MB) during gemm1, then y2 (33.5 MB)
  unsigned short* Y1   = (unsigned short*)(ws + 50331648);      // 33,554,432 (y1 raw)
  unsigned short* w1b  = (unsigned short*)(ws + 83886080);      // 196,608
  unsigned short* w2b  = (unsigned short*)(ws + 84082688);      // 131,072
  int*            widx = (int*)  (ws + 84213760);               // 786,432
  float*          wwgt = (float*)(ws + 85000192);               // 786,432
  float*          stats= (float*)(ws + 85786624);               // 8 KB
  float4*         kprep= (float4*)(ws + 85794816);              // 262,144
  float *sum1 = stats,        *sq1 = stats + 256;
  float *sum2 = stats + 512,  *sq2 = stats + 768;
  float* out = (float*)d_out;

  // prep: 181248 small items + 524288 kf->bf16 conversions = 705536 threads
  prep_kernel<<<2757, 256, 0, stream>>>(W1, W2, known, kf, w1b, w2b, stats, kprep, X);
  nn_kernel<<<dim3(128, 8), 512, 0, stream>>>(unknown, kprep, widx, wwgt);
  // gemm1: fused interp from bf16 kf (X region); batch->XCD swizzle; 8 waves/block
  gemm1_fused<<<1024, 512, 0, stream>>>(X, uf, widx, wwgt, w1b, b1, Y1, sum1, sq1);
  // gemm2: BN1 finalized in-kernel; fused BN1+ReLU on A; y2 -> X; 8 waves/block
  gemm2_kernel<<<1024, 512, 0, stream>>>(Y1, w2b, b2, X, sum2, sq2, sum1, sq1, g1, be1);
  // final: BN2 finalized in-kernel; bf16 y2 -> fp32 d_out
  final_kernel<<<8192, 256, 0, stream>>>(X, out, sum2, sq2, g2, be2);
}

// Round 21
// 141.915 us; speedup vs baseline: 1.1048x; 1.0587x over previous
//
#include <hip/hip_runtime.h>

// ---------- problem constants ----------
#define BQ   8
#define NQ   8192      // unknown points per batch
#define MK   2048      // known points per batch
#define C1v  128
#define C2v  256
#define CIN  384
#define HH   256
#define MTOT (BQ*NQ)   // 65536

#define NCHUNK 8       // candidate chunks per nn block (= waves per block)
#define CHSZ   (MK/NCHUNK)   // 256 candidates per chunk

typedef __attribute__((ext_vector_type(8))) __bf16 bf16x8;
typedef __attribute__((ext_vector_type(4))) float f32x4;
typedef __attribute__((ext_vector_type(8))) unsigned short us8;
typedef __attribute__((ext_vector_type(4))) unsigned short us4;
typedef __attribute__((ext_vector_type(2))) unsigned short us2;

__device__ __forceinline__ unsigned short f2bf(float f) {
  unsigned int u = __builtin_bit_cast(unsigned int, f);
  u += 0x7fffu + ((u >> 16) & 1u);           // round-to-nearest-even
  return (unsigned short)(u >> 16);
}
__device__ __forceinline__ float bf2f(unsigned short h) {
  unsigned int u = ((unsigned int)h) << 16;
  return __builtin_bit_cast(float, u);
}

__device__ __forceinline__ void gload16(const void* g, void* l) {
  __builtin_amdgcn_global_load_lds((const __attribute__((address_space(1))) void*)g,
                                   (__attribute__((address_space(3))) void*)l, 16, 0, 0);
}

// packed f32->bf16 RNE convert (dst.lo = src0, dst.hi = src1)
__device__ __forceinline__ unsigned int cvtpk_bf16(float lo, float hi) {
  unsigned int r;
  asm("v_cvt_pk_bf16_f32 %0, %1, %2" : "=v"(r) : "v"(lo), "v"(hi));
  return r;
}

// LDS chunk swizzle: chunk c = row*8 + col8 -> col8 ^= (row & 7).
// Involution; spreads the 16-lane same-column ds_read_b128 across 8 bank
// groups (16-way conflict -> 2-way, which is free).
__device__ __forceinline__ int swzc(int c) { return c ^ ((c >> 3) & 7); }

// score from a staged candidate: s = u.k - 0.5|k|^2  (kprep.w = -0.5|k|^2)
#define SCORE(k4) (fmaf((k4).x, ux, fmaf((k4).y, uy, (k4).z * uz)) + (k4).w)

// pack fp32 score + candidate index into one exactly-ordered f64 key:
// (double)s has 29 zero low mantissa bits; OR in (2047-j). Distinct fp32
// scores keep exact order; equal scores tie-break to smaller j (top_k rule).
__device__ __forceinline__ double packsd(float s, int negj) {
  unsigned long long u = __builtin_bit_cast(unsigned long long, (double)s)
                       | (unsigned long long)(unsigned int)negj;
  return __builtin_bit_cast(double, u);
}

// 5-op f64 top-3 insert (keys are all distinct): {s0,s1,s2} <- top3 of {s0,s1,s2,t}
#define INS3D(s0, s1, s2, t)                                  \
  do {                                                        \
    double _hi0 = fmax(s0, (t)), _lo0 = fmin(s0, (t));        \
    double _hi1 = fmax(s1, _lo0), _lo1 = fmin(s1, _lo0);      \
    s0 = _hi0; s1 = _hi1; s2 = fmax(s2, _lo1);                \
  } while (0)

// ---------- 1. prep: W->bf16, BN accum zero, kprep, kf->bf16 (kfb) ----------
__global__ __launch_bounds__(256)
void prep_kernel(const float* __restrict__ W1, const float* __restrict__ W2,
                 const float* __restrict__ known, const float* __restrict__ kf,
                 unsigned short* __restrict__ w1b, unsigned short* __restrict__ w2b,
                 float* __restrict__ stats, float4* __restrict__ kprep,
                 unsigned short* __restrict__ kfb) {
  int i = blockIdx.x * 256 + threadIdx.x;
  if (i < HH*CIN) w1b[i] = f2bf(W1[i]);
  else if (i < HH*CIN + HH*HH) w2b[i - HH*CIN] = f2bf(W2[i - HH*CIN]);
  int z = i - (HH*CIN + HH*HH);
  if (z >= 0 && z < 1024) stats[z] = 0.f;
  int z2 = i - (HH*CIN + HH*HH + 1024);
  if (z2 >= 0 && z2 < BQ*MK) {
    const float* kp = known + (size_t)z2 * 3;
    float x = kp[0], y = kp[1], zz = kp[2];
    kprep[z2] = make_float4(x, y, zz, -0.5f*(x*x + y*y + zz*zz));
  }
  int z3 = i - (HH*CIN + HH*HH + 1024 + BQ*MK);
  if (z3 >= 0 && z3 < (BQ*MK*C2v)/8) {
    const float4* src = (const float4*)(kf + (size_t)z3 * 8);
    float4 v0 = src[0], v1 = src[1];
    us8 o;
    o[0]=f2bf(v0.x); o[1]=f2bf(v0.y); o[2]=f2bf(v0.z); o[3]=f2bf(v0.w);
    o[4]=f2bf(v1.x); o[5]=f2bf(v1.y); o[6]=f2bf(v1.z); o[7]=f2bf(v1.w);
    *(us8*)(kfb + (size_t)z3 * 8) = o;
  }
}

// ---------- 2. three_nn: single pass, index-packed f64 keys (round-14 proven) ----------
__global__ __launch_bounds__(512)
void nn_kernel(const float* __restrict__ unknown, const float4* __restrict__ kprep,
               int* __restrict__ widx, float* __restrict__ wwgt) {
  __shared__ double pd[NCHUNK][64][3];      // per-chunk packed triples (12 KB)
  const int b = blockIdx.y;
  const int tid = threadIdx.x;
  const int wave = tid >> 6, lane = tid & 63;

  const int q = blockIdx.x * 64 + lane;
  const float* up = unknown + ((size_t)b * NQ + q) * 3;
  const float ux = up[0], uy = up[1], uz = up[2];
  const float nu = ux*ux + uy*uy + uz*uz;
  const int jbase = wave * CHSZ;
  // wave-uniform chunk pointer -> scalar-path candidate fetch
  const float4* cp = kprep + (b << 11) + __builtin_amdgcn_readfirstlane(jbase);

  // dual accumulator sets for ILP; keys are distinct so merge order is free
  double A0=-1e300, A1=-1e300, A2=-1e300;
  double B0=-1e300, B1=-1e300, B2=-1e300;
  #pragma unroll 4
  for (int j = 0; j < CHSZ; j += 2) {
    float4 ka = cp[j];
    float4 kc = cp[j+1];
    float sA = SCORE(ka);
    float sB = SCORE(kc);
    double da = packsd(sA, 2047 - (jbase + j));
    double db = packsd(sB, 2047 - (jbase + j + 1));
    INS3D(A0, A1, A2, da);
    INS3D(B0, B1, B2, db);
  }
  INS3D(A0, A1, A2, B0);
  INS3D(A0, A1, A2, B1);
  INS3D(A0, A1, A2, B2);
  pd[wave][lane][0] = A0; pd[wave][lane][1] = A1; pd[wave][lane][2] = A2;
  __syncthreads();

  if (tid < 64) {   // wave 0: lane == query; merge the 8 chunk triples
    double f0=-1e300, f1=-1e300, f2=-1e300;
    #pragma unroll
    for (int c = 0; c < NCHUNK; ++c) {
      INS3D(f0, f1, f2, pd[c][tid][0]);
      INS3D(f0, f1, f2, pd[c][tid][1]);
      INS3D(f0, f1, f2, pd[c][tid][2]);
    }
    unsigned long long u0 = __builtin_bit_cast(unsigned long long, f0);
    unsigned long long u1 = __builtin_bit_cast(unsigned long long, f1);
    unsigned long long u2 = __builtin_bit_cast(unsigned long long, f2);
    int x0 = 2047 - (int)(u0 & 2047ULL);
    int x1 = 2047 - (int)(u1 & 2047ULL);
    int x2 = 2047 - (int)(u2 & 2047ULL);
    // masking restores the exact fp32 score bits
    float s0 = (float)__builtin_bit_cast(double, u0 & ~2047ULL);
    float s1 = (float)__builtin_bit_cast(double, u1 & ~2047ULL);
    float s2 = (float)__builtin_bit_cast(double, u2 & ~2047ULL);
    float d0 = sqrtf(fmaxf(nu - 2.f*s0, 0.f)) + 1e-10f;
    float d1 = sqrtf(fmaxf(nu - 2.f*s1, 0.f)) + 1e-10f;
    float d2 = sqrtf(fmaxf(nu - 2.f*s2, 0.f)) + 1e-10f;
    float r0 = 1.f/d0, r1 = 1.f/d1, r2 = 1.f/d2;
    float rs = 1.f/(r0 + r1 + r2);
    size_t p = (size_t)b * NQ + q;
    widx[p*3+0] = x0;    widx[p*3+1] = x1;    widx[p*3+2] = x2;
    wwgt[p*3+0] = r0*rs; wwgt[p*3+1] = r1*rs; wwgt[p*3+2] = r2*rs;
  }
}

// ---------- 3. GEMM1 (fused interp), 8 waves/block, LDS XOR-swizzled tiles.
// A built in-staging from bf16-kf gathers + uf concat; ds_write goes to the
// swizzled slot. B uses global_load_lds with LINEAR dest + inverse-swizzled
// global source column (rule: both-sides-or-neither). MFMA reads XOR the
// column chunk with row&7. Pure static permutation -- bit-identical data.
__global__ __launch_bounds__(512)
void gemm1_fused(const unsigned short* __restrict__ kfb, const float* __restrict__ uf,
                 const int* __restrict__ widx, const float* __restrict__ wwgt,
                 const unsigned short* __restrict__ Bw,
                 const float* __restrict__ bias,
                 unsigned short* __restrict__ Out,
                 float* __restrict__ gsum, float* __restrict__ gsq) {
  constexpr int K = CIN;
  __shared__ unsigned short As[128][64];   // 16 KB
  __shared__ unsigned short Bs[128][64];   // 16 KB
  const int tid  = threadIdx.x;
  const int lane = tid & 63;
  const int wave = tid >> 6;          // 0..7
  const int wid   = blockIdx.x;
  const int batch = wid & 7;          // -> XCD id
  const int inner = wid >> 3;         // 0..127 within batch
  const int bm = batch * 64 + (inner >> 1);
  const int bn = inner & 1;
  const int wm = wave >> 1;           // 0..3: 32-row slice
  const int wn = wave & 1;            // 0..1: 64-col slice

  // prologue: per-chunk gather byte-offsets + weights (chunk i -> fixed row/col)
  unsigned int voK0[2], voK1[2], voK2[2], voU[2];
  float w0r[2], w1r[2], w2r[2];
  #pragma unroll
  for (int i = 0; i < 2; ++i) {
    const int c = i*512 + tid;
    const int row = c >> 3;
    const int colK = (c & 7) * 16;     // byte offset within 512 B bf16 row
    const int colU = (c & 7) * 32;     // byte offset within 512 B fp32 row
    const int p = bm*128 + row;
    const int b = p >> 13;
    w0r[i] = wwgt[p*3+0]; w1r[i] = wwgt[p*3+1]; w2r[i] = wwgt[p*3+2];
    voK0[i] = ((unsigned)((b << 11) + widx[p*3+0]) << 9) + colK;
    voK1[i] = ((unsigned)((b << 11) + widx[p*3+1]) << 9) + colK;
    voK2[i] = ((unsigned)((b << 11) + widx[p*3+2]) << 9) + colK;
    voU[i]  = (unsigned)p * 512u + colU;
  }

  f32x4 acc[2][4];
  const f32x4 zero = {0.f, 0.f, 0.f, 0.f};
  #pragma unroll
  for (int m = 0; m < 2; ++m)
    #pragma unroll
    for (int n = 0; n < 4; ++n) acc[m][n] = zero;

  const char* kfbb = (const char*)kfb;
  const char* ufb  = (const char*)uf;

  #pragma unroll
  for (int t = 0; t < 6; ++t) {
    const int k0 = t * 64;
    // B-tile: async LDS-direct, linear dest; source column inverse-swizzled
    #pragma unroll
    for (int i = 0; i < 2; ++i) {
      const int cbase = i*512 + wave*64;
      const int c = cbase + lane;
      const int brow = c >> 3;
      const int bcol = (((c & 7) ^ (brow & 7))) * 8;   // logical col of slot c
      gload16(Bw + ((size_t)(bn*128 + brow))*K + k0 + bcol, (unsigned short*)Bs + cbase*8);
    }
    // A-tile: load all gathers for this iteration, then lerp/convert/write
    if (t < 4) {
      us8 GA[2], GE[2], GG[2];
      #pragma unroll
      for (int i = 0; i < 2; ++i) {
        GA[i] = *(const us8*)(kfbb + voK0[i] + t*128);
        GE[i] = *(const us8*)(kfbb + voK1[i] + t*128);
        GG[i] = *(const us8*)(kfbb + voK2[i] + t*128);
      }
      #pragma unroll
      for (int i = 0; i < 2; ++i) {
        const int c = i*512 + tid;
        const float w0 = w0r[i], w1 = w1r[i], w2 = w2r[i];
        float r[8];
        #pragma unroll
        for (int j = 0; j < 8; ++j) {
          float fa = bf2f((unsigned short)GA[i][j]);
          float fe = bf2f((unsigned short)GE[i][j]);
          float fg = bf2f((unsigned short)GG[i][j]);
          r[j] = w0*fa + w1*fe + w2*fg;
        }
        uint4 ov;
        ov.x = cvtpk_bf16(r[0], r[1]);
        ov.y = cvtpk_bf16(r[2], r[3]);
        ov.z = cvtpk_bf16(r[4], r[5]);
        ov.w = cvtpk_bf16(r[6], r[7]);
        *(uint4*)((unsigned short*)As + (size_t)swzc(c)*8) = ov;
      }
    } else {
      float4 U0[2], U1[2];
      #pragma unroll
      for (int i = 0; i < 2; ++i) {
        U0[i] = *(const float4*)(ufb + voU[i] + (t-4)*256);
        U1[i] = *(const float4*)(ufb + voU[i] + (t-4)*256 + 16);
      }
      #pragma unroll
      for (int i = 0; i < 2; ++i) {
        const int c = i*512 + tid;
        uint4 ov;
        ov.x = cvtpk_bf16(U0[i].x, U0[i].y);
        ov.y = cvtpk_bf16(U0[i].z, U0[i].w);
        ov.z = cvtpk_bf16(U1[i].x, U1[i].y);
        ov.w = cvtpk_bf16(U1[i].z, U1[i].w);
        *(uint4*)((unsigned short*)As + (size_t)swzc(c)*8) = ov;
      }
    }
    __syncthreads();
    const int kq = (lane >> 4) * 8;
    #pragma unroll
    for (int kk = 0; kk < 64; kk += 32) {
      const int col8 = (kk + kq) >> 3;
      bf16x8 af[2], bfr[4];
      #pragma unroll
      for (int m = 0; m < 2; ++m) {
        const int arow = wm*32 + m*16 + (lane & 15);
        af[m] = *(const bf16x8*)&As[arow][(col8 ^ (arow & 7)) << 3];
      }
      #pragma unroll
      for (int n = 0; n < 4; ++n) {
        const int brow = wn*64 + n*16 + (lane & 15);
        bfr[n] = *(const bf16x8*)&Bs[brow][(col8 ^ (brow & 7)) << 3];
      }
      #pragma unroll
      for (int m = 0; m < 2; ++m)
        #pragma unroll
        for (int n = 0; n < 4; ++n)
          acc[m][n] = __builtin_amdgcn_mfma_f32_16x16x32_bf16(af[m], bfr[n], acc[m][n], 0, 0, 0);
    }
    __syncthreads();
  }

  // epilogue: bias, store bf16, per-channel sum/sumsq (per-wm partials)
  float* s_sum = (float*)&As[0][0];   // [4][128]
  float* s_sq  = s_sum + 512;         // [4][128]
  #pragma unroll
  for (int n = 0; n < 4; ++n) {
    const int cb   = wn*64 + n*16 + (lane & 15);
    const int gcol = bn*128 + cb;
    const float bv = bias[gcol];
    float sum = 0.f, sq = 0.f;
    #pragma unroll
    for (int m = 0; m < 2; ++m) {
      const size_t grow = (size_t)bm*128 + wm*32 + m*16 + (lane >> 4)*4;
      #pragma unroll
      for (int qq = 0; qq < 4; ++qq) {
        float y = acc[m][n][qq] + bv;
        sum += y; sq += y*y;
        Out[(grow+qq)*256 + gcol] = f2bf(y);
      }
    }
    sum += __shfl_xor(sum, 16, 64); sum += __shfl_xor(sum, 32, 64);
    sq  += __shfl_xor(sq , 16, 64); sq  += __shfl_xor(sq , 32, 64);
    if (lane < 16) { s_sum[wm*128 + cb] = sum; s_sq[wm*128 + cb] = sq; }
  }
  __syncthreads();
  if (tid < 128) {
    float ts = s_sum[tid] + s_sum[128+tid] + s_sum[256+tid] + s_sum[384+tid];
    float tq = s_sq [tid] + s_sq [128+tid] + s_sq [256+tid] + s_sq [384+tid];
    atomicAdd(&gsum[bn*128 + tid], ts);
    atomicAdd(&gsq [bn*128 + tid], tq);
  }
}

// ---------- 4. GEMM2, 8 waves/block, LDS XOR-swizzled tiles (mirrors gemm1):
// fused BN1+ReLU on A-load (scale/shift computed in preamble from raw sums),
// y2 bf16 out, + BN2 stats ----------
__global__ __launch_bounds__(512)
void gemm2_kernel(const unsigned short* __restrict__ A,     // y1 raw bf16
                  const unsigned short* __restrict__ Bw,    // W2 bf16
                  const float* __restrict__ bias,           // b2
                  unsigned short* __restrict__ Out,         // y2 bf16
                  float* __restrict__ gsum, float* __restrict__ gsq,     // BN2 accum
                  const float* __restrict__ gsum1, const float* __restrict__ gsq1,
                  const float* __restrict__ g1, const float* __restrict__ be1) {
  constexpr int K = HH;
  __shared__ unsigned short As[128][64];   // 16 KB
  __shared__ unsigned short Bs[128][64];   // 16 KB
  __shared__ float sc_l[HH], sh_l[HH];     // 2 KB
  const int tid  = threadIdx.x;
  const int lane = tid & 63;
  const int wave = tid >> 6;          // 0..7
  const int wid  = blockIdx.x;
  const int slot = wid & 15;
  const int bm = ((wid >> 4) << 3) | (slot & 7);
  const int bn = slot >> 3;
  const int wm = wave >> 1;           // 0..3: 32-row slice
  const int wn = wave & 1;            // 0..1: 64-col slice

  if (tid < HH) {  // BN1 finalize (redundant per block; replaces stats_fin dispatch)
    float mu  = gsum1[tid] * (1.f/65536.f);
    float var = gsq1[tid]  * (1.f/65536.f) - mu*mu;
    float sc  = g1[tid] * rsqrtf(var + 1e-5f);
    sc_l[tid] = sc;
    sh_l[tid] = be1[tid] - mu*sc;
  }
  __syncthreads();

  f32x4 acc[2][4];
  const f32x4 zero = {0.f, 0.f, 0.f, 0.f};
  #pragma unroll
  for (int m = 0; m < 2; ++m)
    #pragma unroll
    for (int n = 0; n < 4; ++n) acc[m][n] = zero;

  #pragma unroll
  for (int t = 0; t < 4; ++t) {
    const int k0 = t * 64;
    // B-tile: async LDS-direct, linear dest; source column inverse-swizzled
    #pragma unroll
    for (int i = 0; i < 2; ++i) {
      const int cbase = i*512 + wave*64;
      const int c = cbase + lane;
      const int brow = c >> 3;
      const int bcol = (((c & 7) ^ (brow & 7))) * 8;   // logical col of slot c
      gload16(Bw + ((size_t)(bn*128 + brow))*K + k0 + bcol, (unsigned short*)Bs + cbase*8);
    }
    // A-tile: 2 chunks/thread, BN1+ReLU fused, write to swizzled slot
    us8 V[2];
    #pragma unroll
    for (int i = 0; i < 2; ++i) {
      const int c = i*512 + tid;
      const int row = c >> 3, col = (c & 7) * 8;
      V[i] = *(const us8*)(A + ((size_t)(bm*128 + row))*K + k0 + col);
    }
    #pragma unroll
    for (int i = 0; i < 2; ++i) {
      const int c = i*512 + tid;
      const int col = (c & 7) * 8;
      us8 o;
      #pragma unroll
      for (int j = 0; j < 8; ++j) {
        float y = fmaxf(fmaf(bf2f((unsigned short)V[i][j]), sc_l[k0+col+j], sh_l[k0+col+j]), 0.f);
        o[j] = f2bf(y);
      }
      *(us8*)((unsigned short*)As + (size_t)swzc(c)*8) = o;
    }
    __syncthreads();
    const int kq = (lane >> 4) * 8;
    #pragma unroll
    for (int kk = 0; kk < 64; kk += 32) {
      const int col8 = (kk + kq) >> 3;
      bf16x8 af[2], bfr[4];
      #pragma unroll
      for (int m = 0; m < 2; ++m) {
        const int arow = wm*32 + m*16 + (lane & 15);
        af[m] = *(const bf16x8*)&As[arow][(col8 ^ (arow & 7)) << 3];
      }
      #pragma unroll
      for (int n = 0; n < 4; ++n) {
        const int brow = wn*64 + n*16 + (lane & 15);
        bfr[n] = *(const bf16x8*)&Bs[brow][(col8 ^ (brow & 7)) << 3];
      }
      #pragma unroll
      for (int m = 0; m < 2; ++m)
        #pragma unroll
        for (int n = 0; n < 4; ++n)
          acc[m][n] = __builtin_amdgcn_mfma_f32_16x16x32_bf16(af[m], bfr[n], acc[m][n], 0, 0, 0);
    }
    __syncthreads();
  }

  // epilogue: bias, store bf16 y2, per-channel sum/sumsq (per-wm partials)
  float* s_sum = (float*)&As[0][0];   // [4][128]
  float* s_sq  = s_sum + 512;         // [4][128]
  #pragma unroll
  for (int n = 0; n < 4; ++n) {
    const int cb   = wn*64 + n*16 + (lane & 15);
    const int gcol = bn*128 + cb;
    const float bv = bias[gcol];
    float sum = 0.f, sq = 0.f;
    #pragma unroll
    for (int m = 0; m < 2; ++m) {
      const size_t grow = (size_t)bm*128 + wm*32 + m*16 + (lane >> 4)*4;
      #pragma unroll
      for (int qq = 0; qq < 4; ++qq) {
        float y = acc[m][n][qq] + bv;
        sum += y; sq += y*y;
        Out[(grow+qq)*256 + gcol] = f2bf(y);
      }
    }
    sum += __shfl_xor(sum, 16, 64); sum += __shfl_xor(sum, 32, 64);
    sq  += __shfl_xor(sq , 16, 64); sq  += __shfl_xor(sq , 32, 64);
    if (lane < 16) { s_sum[wm*128 + cb] = sum; s_sq[wm*128 + cb] = sq; }
  }
  __syncthreads();
  if (tid < 128) {
    float ts = s_sum[tid] + s_sum[128+tid] + s_sum[256+tid] + s_sum[384+tid];
    float tq = s_sq [tid] + s_sq [128+tid] + s_sq [256+tid] + s_sq [384+tid];
    atomicAdd(&gsum[bn*128 + tid], ts);
    atomicAdd(&gsq [bn*128 + tid], tq);
  }
}

// ---------- 5. final BN2+ReLU: bf16 y2 -> fp32 d_out (scale/shift in preamble) ----------
__global__ __launch_bounds__(256)
void final_kernel(const unsigned short* __restrict__ Y2, float* __restrict__ Out,
                  const float* __restrict__ gsum, const float* __restrict__ gsq,
                  const float* __restrict__ g2, const float* __restrict__ be2) {
  __shared__ float sc[256], sh[256];
  {  // BN2 finalize (redundant per block; replaces stats_fin dispatch)
    float mu  = gsum[threadIdx.x] * (1.f/65536.f);
    float var = gsq[threadIdx.x]  * (1.f/65536.f) - mu*mu;
    float scv = g2[threadIdx.x] * rsqrtf(var + 1e-5f);
    sc[threadIdx.x] = scv;
    sh[threadIdx.x] = be2[threadIdx.x] - mu*scv;
  }
  __syncthreads();
  size_t i = ((size_t)blockIdx.x * 256 + threadIdx.x) * 8;
  int c0 = (int)(i & 255);
  us8 v = *(const us8*)(Y2 + i);
  float4 o1, o2;
  o1.x = fmaxf(fmaf(bf2f(v[0]), sc[c0+0], sh[c0+0]), 0.f);
  o1.y = fmaxf(fmaf(bf2f(v[1]), sc[c0+1], sh[c0+1]), 0.f);
  o1.z = fmaxf(fmaf(bf2f(v[2]), sc[c0+2], sh[c0+2]), 0.f);
  o1.w = fmaxf(fmaf(bf2f(v[3]), sc[c0+3], sh[c0+3]), 0.f);
  o2.x = fmaxf(fmaf(bf2f(v[4]), sc[c0+4], sh[c0+4]), 0.f);
  o2.y = fmaxf(fmaf(bf2f(v[5]), sc[c0+5], sh[c0+5]), 0.f);
  o2.z = fmaxf(fmaf(bf2f(v[6]), sc[c0+6], sh[c0+6]), 0.f);
  o2.w = fmaxf(fmaf(bf2f(v[7]), sc[c0+7], sh[c0+7]), 0.f);
  *(float4*)(Out + i)     = o1;
  *(float4*)(Out + i + 4) = o2;
}

// ---------- launch ----------
extern "C" void kernel_launch(void* const* d_in, const int* in_sizes, int n_in,
                              void* d_out, int out_size, void* d_ws, size_t ws_size,
                              hipStream_t stream) {
  const float* unknown = (const float*)d_in[0];
  const float* known   = (const float*)d_in[1];
  const float* uf      = (const float*)d_in[2];
  const float* kf      = (const float*)d_in[3];
  const float* W1      = (const float*)d_in[4];
  const float* b1      = (const float*)d_in[5];
  const float* g1      = (const float*)d_in[6];
  const float* be1     = (const float*)d_in[7];
  const float* W2      = (const float*)d_in[8];
  const float* b2      = (const float*)d_in[9];
  const float* g2      = (const float*)d_in[10];
  const float* be2     = (const float*)d_in[11];

  char* ws = (char*)d_ws;
  unsigned short* X    = (unsigned short*)(ws);                 // kfb (8.4 MB) during gemm1, then y2 (33.5 MB)
  unsigned short* Y1   = (unsigned short*)(ws + 50331648);      // 33,554,432 (y1 raw)
  unsigned short* w1b  = (unsigned short*)(ws + 83886080);      // 196,608
  unsigned short* w2b  = (unsigned short*)(ws + 84082688);      // 131,072
  int*            widx = (int*)  (ws + 84213760);               // 786,432
  float*          wwgt = (float*)(ws + 85000192);               // 786,432
  float*          stats= (float*)(ws + 85786624);               // 8 KB
  float4*         kprep= (float4*)(ws + 85794816);              // 262,144
  float *sum1 = stats,        *sq1 = stats + 256;
  float *sum2 = stats + 512,  *sq2 = stats + 768;
  float* out = (float*)d_out;

  // prep: 181248 small items + 524288 kf->bf16 conversions = 705536 threads
  prep_kernel<<<2757, 256, 0, stream>>>(W1, W2, known, kf, w1b, w2b, stats, kprep, X);
  nn_kernel<<<dim3(128, 8), 512, 0, stream>>>(unknown, kprep, widx, wwgt);
  // gemm1: fused interp from bf16 kf (X region); batch->XCD swizzle; 8 waves/block
  gemm1_fused<<<1024, 512, 0, stream>>>(X, uf, widx, wwgt, w1b, b1, Y1, sum1, sq1);
  // gemm2: BN1 finalized in-kernel; fused BN1+ReLU on A; y2 -> X; 8 waves/block
  gemm2_kernel<<<1024, 512, 0, stream>>>(Y1, w2b, b2, X, sum2, sq2, sum1, sq1, g1, be1);
  // final: BN2 finalized in-kernel; bf16 y2 -> fp32 d_out
  final_kernel<<<8192, 256, 0, stream>>>(X, out, sum2, sq2, g2, be2);
}